// Round 11
// baseline (129.612 us; speedup 1.0000x reference)
//
#include <hip/hip_runtime.h>
#include <hip/hip_bf16.h>
#include <cstdint>

// B=8, S=1024, D=512, H=8, DK=64. All-bf16 MFMA pipeline.
// R11: gm tensor deleted. attn reads mask/gprob DIRECTLY (L3-resident,
// shared across the 8 heads of each b); prep converts only q/k/v/W.
// attn otherwise R5-exact (best measured structure, 49.8us).

typedef __attribute__((ext_vector_type(8))) short short8;
typedef __attribute__((ext_vector_type(4))) float f32x4;

__device__ __forceinline__ ushort f2bf(float x) {
    union { __hip_bfloat16 h; ushort u; } v;
    v.h = __float2bfloat16(x);
    return v.u;
}
__device__ __forceinline__ uint cvtpk(float lo, float hi) {
    uint r;
    asm("v_cvt_pk_bf16_f32 %0, %1, %2" : "=v"(r) : "v"(lo), "v"(hi));
    return r;
}
__device__ __forceinline__ f32x4 mfma16(short8 a, short8 b, f32x4 c) {
    return __builtin_amdgcn_mfma_f32_16x16x32_bf16(a, b, c, 0, 0, 0);
}
// async global->LDS, 16B per lane. LDS dest = wave-uniform base + lane*16.
__device__ __forceinline__ void gl16(const void* g, const void* l) {
    __builtin_amdgcn_global_load_lds(
        (const __attribute__((address_space(1))) uint32_t*)(uintptr_t)g,
        (__attribute__((address_space(3))) uint32_t*)(uint32_t)(uintptr_t)l,
        16, 0, 0);
}

// load mask row chunk: ints at +0..3, +4..7, +32..35, +36..39
__device__ __forceinline__ void ld16i(const int* p, int (&d)[16]) {
    int4 a = *(const int4*)p,       b = *(const int4*)(p + 4);
    int4 c = *(const int4*)(p + 32), e = *(const int4*)(p + 36);
    d[0]=a.x; d[1]=a.y; d[2]=a.z;  d[3]=a.w;
    d[4]=b.x; d[5]=b.y; d[6]=b.z;  d[7]=b.w;
    d[8]=c.x; d[9]=c.y; d[10]=c.z; d[11]=c.w;
    d[12]=e.x; d[13]=e.y; d[14]=e.z; d[15]=e.w;
}
__device__ __forceinline__ void ld16f(const float* p, float (&d)[16]) {
    float4 a = *(const float4*)p,        b = *(const float4*)(p + 4);
    float4 c = *(const float4*)(p + 32), e = *(const float4*)(p + 36);
    d[0]=a.x; d[1]=a.y; d[2]=a.z;  d[3]=a.w;
    d[4]=b.x; d[5]=b.y; d[6]=b.z;  d[7]=b.w;
    d[8]=c.x; d[9]=c.y; d[10]=c.z; d[11]=c.w;
    d[12]=e.x; d[13]=e.y; d[14]=e.z; d[15]=e.w;
}

// ---------------------------------------------------------------------------
// prep: [0,12288)      convert query/key/value fp32 -> bf16 flat [8192][512]
//       [12288,13312)  convert Wq,Wk,Wv,Wh fp32 -> bf16 [512][512]
// ---------------------------------------------------------------------------
__global__ __launch_bounds__(256)
void prep(const float* __restrict__ q, const float* __restrict__ k,
          const float* __restrict__ v,
          const float* __restrict__ wq, const float* __restrict__ wk,
          const float* __restrict__ wv, const float* __restrict__ wh,
          ushort* __restrict__ qb, ushort* __restrict__ kb,
          ushort* __restrict__ vb,
          ushort* __restrict__ wqb, ushort* __restrict__ wkb,
          ushort* __restrict__ wvb, ushort* __restrict__ whb)
{
    const int bid = blockIdx.x, tid = threadIdx.x;
    if (bid < 12288) {
        size_t id = ((size_t)bid * 256 + tid) * 4;
        int t = (int)(id >> 22);
        size_t off = id & 4194303;
        const float* s = (t == 0) ? q : (t == 1) ? k : v;
        ushort* d = (t == 0) ? qb : (t == 1) ? kb : vb;
        float4 x = *(const float4*)(s + off);
        uint2 o; o.x = cvtpk(x.x, x.y); o.y = cvtpk(x.z, x.w);
        *(uint2*)(d + off) = o;
    } else {
        size_t id = ((size_t)(bid - 12288) * 256 + tid) * 4;
        int t = (int)(id >> 18);
        size_t off = id & 262143;
        const float* s = (t == 0) ? wq : (t == 1) ? wk : (t == 2) ? wv : wh;
        ushort* d = (t == 0) ? wqb : (t == 1) ? wkb : (t == 2) ? wvb : whb;
        float4 x = *(const float4*)(s + off);
        uint2 o; o.x = cvtpk(x.x, x.y); o.y = cvtpk(x.z, x.w);
        *(uint2*)(d + off) = o;
    }
}

// ---------------------------------------------------------------------------
// QKV GEMM (unchanged, known-good)
// ---------------------------------------------------------------------------
__global__ __launch_bounds__(256, 2)
void gemm3(const ushort* __restrict__ qb, const ushort* __restrict__ kb,
           const ushort* __restrict__ vb,
           const ushort* __restrict__ Wqb, const ushort* __restrict__ Wkb,
           const ushort* __restrict__ Wvb,
           ushort* __restrict__ q_ws, ushort* __restrict__ k_ws,
           ushort* __restrict__ vT)
{
    __shared__ __attribute__((aligned(16))) ushort As[8192];
    __shared__ __attribute__((aligned(16))) ushort Bs[8192];

    const int z = blockIdx.z;
    const ushort* A = (z == 0) ? qb : (z == 1) ? kb : Wvb;
    const ushort* B = (z == 0) ? Wqb : (z == 1) ? Wkb : vb;
    const int mt = (z == 2) ? blockIdx.y : blockIdx.x;
    const int nt = (z == 2) ? blockIdx.x : blockIdx.y;
    const int m0 = mt * 128, n0 = nt * 128;
    const int tid = threadIdx.x, lane = tid & 63, wave = tid >> 6;
    const int l15 = lane & 15, g = lane >> 4;
    const int wm = wave >> 1, wn = wave & 1;

    const int cb = (lane & 7) << 4;
    int soff[4];
    #pragma unroll
    for (int it = 0; it < 4; ++it) {
        int r = (it * 4 + wave) * 8 + (lane >> 3);
        soff[it] = r * 1024 + (cb ^ ((r & 7) << 4));
    }
    const char* Ab = (const char*)A + (size_t)m0 * 1024;
    const char* Bb = (const char*)B + (size_t)n0 * 1024;

    const int sw = (l15 & 7) << 4;
    const int c0 = (g * 16) ^ sw;
    const int c1 = (64 + g * 16) ^ sw;

    f32x4 acc[4][4];
    #pragma unroll
    for (int i = 0; i < 4; ++i)
        #pragma unroll
        for (int j = 0; j < 4; ++j) acc[i][j] = (f32x4){0.f, 0.f, 0.f, 0.f};

    for (int ks = 0; ks < 8; ++ks) {
        const int kof = ks * 128;
        #pragma unroll
        for (int it = 0; it < 4; ++it) {
            gl16(Ab + soff[it] + kof, (const char*)As + (it * 4 + wave) * 1024);
            gl16(Bb + soff[it] + kof, (const char*)Bs + (it * 4 + wave) * 1024);
        }
        __syncthreads();
        #pragma unroll
        for (int kk = 0; kk < 2; ++kk) {
            const int cc = kk ? c1 : c0;
            short8 af[4], bf[4];
            #pragma unroll
            for (int i = 0; i < 4; ++i)
                af[i] = *(const short8*)((const char*)As + (wm * 64 + i * 16 + l15) * 128 + cc);
            #pragma unroll
            for (int j = 0; j < 4; ++j)
                bf[j] = *(const short8*)((const char*)Bs + (wn * 64 + j * 16 + l15) * 128 + cc);
            #pragma unroll
            for (int i = 0; i < 4; ++i)
                #pragma unroll
                for (int j = 0; j < 4; ++j)
                    acc[i][j] = mfma16(af[i], bf[j], acc[i][j]);
        }
        __syncthreads();
    }

    #pragma unroll
    for (int i = 0; i < 4; ++i) {
        #pragma unroll
        for (int j = 0; j < 4; ++j) {
            #pragma unroll
            for (int r = 0; r < 4; ++r) {
                int mm = m0 + wm * 64 + i * 16 + g * 4 + r;
                int nn = n0 + wn * 64 + j * 16 + l15;
                float val = acc[i][j][r];
                if (z == 0) {
                    val *= 0.18033688f;   // 1/sqrt(64) * log2(e) folded into Q
                    int b = mm >> 10, s = mm & 1023, h = nn >> 6, dk = nn & 63;
                    q_ws[((((size_t)(b * 8 + h)) << 10) + s) * 64 + dk] = f2bf(val);
                } else if (z == 1) {
                    int b = mm >> 10, s = mm & 1023, h = nn >> 6, dk = nn & 63;
                    k_ws[((((size_t)(b * 8 + h)) << 10) + s) * 64 + dk] = f2bf(val);
                } else {
                    int h = mm >> 6, d = mm & 63, b = nn >> 10, s = nn & 1023;
                    vT[(((size_t)(b * 8 + h) * 64 + d) << 10) + s] = f2bf(val);
                }
            }
        }
    }
}

// ---------------------------------------------------------------------------
// Out projection (unchanged, known-good)
// ---------------------------------------------------------------------------
__global__ __launch_bounds__(256, 2)
void gemm_o(const ushort* __restrict__ Xh, const ushort* __restrict__ Whb,
            const float* __restrict__ bias, float* __restrict__ out)
{
    __shared__ __attribute__((aligned(16))) ushort As[8192];
    __shared__ __attribute__((aligned(16))) ushort Bs[8192];

    const int m0 = blockIdx.x * 128, n0 = blockIdx.y * 128;
    const int tid = threadIdx.x, lane = tid & 63, wave = tid >> 6;
    const int l15 = lane & 15, g = lane >> 4;
    const int wm = wave >> 1, wn = wave & 1;
    const int bb = m0 >> 10, s0 = m0 & 1023;

    const int cb = (lane & 7) << 4;
    int aoff[4], boff[4];
    #pragma unroll
    for (int it = 0; it < 4; ++it) {
        int r = (it * 4 + wave) * 8 + (lane >> 3);
        int swz = cb ^ ((r & 7) << 4);
        aoff[it] = ((bb * 8) * 1024 + s0 + r) * 128 + swz;  // +ks*131072
        boff[it] = (n0 + r) * 1024 + swz;                   // +ks*128
    }
    const int sw = (l15 & 7) << 4;
    const int c0 = (g * 16) ^ sw;
    const int c1 = (64 + g * 16) ^ sw;

    f32x4 acc[4][4];
    #pragma unroll
    for (int i = 0; i < 4; ++i)
        #pragma unroll
        for (int j = 0; j < 4; ++j) acc[i][j] = (f32x4){0.f, 0.f, 0.f, 0.f};

    for (int ks = 0; ks < 8; ++ks) {
        #pragma unroll
        for (int it = 0; it < 4; ++it) {
            gl16((const char*)Xh + aoff[it] + ks * 131072,
                 (const char*)As + (it * 4 + wave) * 1024);
            gl16((const char*)Whb + boff[it] + ks * 128,
                 (const char*)Bs + (it * 4 + wave) * 1024);
        }
        __syncthreads();
        #pragma unroll
        for (int kk = 0; kk < 2; ++kk) {
            const int cc = kk ? c1 : c0;
            short8 af[4], bf[4];
            #pragma unroll
            for (int i = 0; i < 4; ++i)
                af[i] = *(const short8*)((const char*)As + (wm * 64 + i * 16 + l15) * 128 + cc);
            #pragma unroll
            for (int j = 0; j < 4; ++j)
                bf[j] = *(const short8*)((const char*)Bs + (wn * 64 + j * 16 + l15) * 128 + cc);
            #pragma unroll
            for (int i = 0; i < 4; ++i)
                #pragma unroll
                for (int j = 0; j < 4; ++j)
                    acc[i][j] = mfma16(af[i], bf[j], acc[i][j]);
        }
        __syncthreads();
    }

    float bv[4];
    #pragma unroll
    for (int j = 0; j < 4; ++j) bv[j] = bias[n0 + wn * 64 + j * 16 + l15];

    #pragma unroll
    for (int i = 0; i < 4; ++i)
        #pragma unroll
        for (int j = 0; j < 4; ++j)
            #pragma unroll
            for (int r = 0; r < 4; ++r) {
                int mm = m0 + wm * 64 + i * 16 + g * 4 + r;
                int nn = n0 + wn * 64 + j * 16 + l15;
                out[(size_t)mm * 512 + nn] = acc[i][j][r] + bv[j];
            }
}

// ---------------------------------------------------------------------------
// attn: R5 structure, but mask/gprob read DIRECTLY (no gm tensor).
// 4 waves x 32 q = 128 q / block, grid 512 (w = qt*64 + bh; XCD = bh%8).
// K/V staged via global_load_lds (sigma row-perm + XOR swizzle on SOURCE),
// double-buffered. Score s4[t4][r] <-> key k = t*64 + (t4>>1)*32 + g*8 +
// (t4&1)*4 + r i.e. jj = c*8+j maps key k = t*64 + c*32 + g*8 + j.
// allowed = mask!=0 || q==k; p = exp2(allowed ? s : -1e9); pg = p*gprob.
// ---------------------------------------------------------------------------
__device__ __forceinline__ void softmax_direct(
    const int (&mm)[16], const float (&gv)[16], int dq,
    const f32x4 (&s4)[4], float& lsum, uint4& u0, uint4& u1)
{
    float p[16];
    #pragma unroll
    for (int jj = 0; jj < 16; ++jj) {
        const int kof = (jj & 7) + ((jj >> 3) << 5);
        const int t4 = ((jj >> 3) << 1) + ((jj & 7) >> 2), r = jj & 3;
        const bool allowed = (mm[jj] != 0) || (kof == dq);
        p[jj] = exp2f(allowed ? s4[t4][r] : -1.0e9f);
    }
    lsum += (((p[0] + p[1]) + (p[2] + p[3])) + ((p[4] + p[5]) + (p[6] + p[7])))
          + (((p[8] + p[9]) + (p[10] + p[11])) + ((p[12] + p[13]) + (p[14] + p[15])));
    u0.x = cvtpk(p[0] * gv[0],  p[1] * gv[1]);
    u0.y = cvtpk(p[2] * gv[2],  p[3] * gv[3]);
    u0.z = cvtpk(p[4] * gv[4],  p[5] * gv[5]);
    u0.w = cvtpk(p[6] * gv[6],  p[7] * gv[7]);
    u1.x = cvtpk(p[8] * gv[8],  p[9] * gv[9]);
    u1.y = cvtpk(p[10] * gv[10], p[11] * gv[11]);
    u1.z = cvtpk(p[12] * gv[12], p[13] * gv[13]);
    u1.w = cvtpk(p[14] * gv[14], p[15] * gv[15]);
}

__global__ __launch_bounds__(256, 2)
void attn(const ushort* __restrict__ Qh, const ushort* __restrict__ Kh,
          const ushort* __restrict__ Vt, const int* __restrict__ mask,
          const float* __restrict__ gp, ushort* __restrict__ xo)
{
    __shared__ __attribute__((aligned(16))) ushort kv[2][2][4096];

    const int w = blockIdx.x;
    const int bh = w & 63, qt = w >> 6;
    const int tid = threadIdx.x, wave = tid >> 6, lane = tid & 63;
    const int l15 = lane & 15, g = lane >> 4;
    const int q0 = qt * 128 + wave * 32;      // this wave: q0..q0+31 (2 frags)
    const int b = bh >> 3;

    const char* Kpb = (const char*)(Kh + (size_t)bh * 65536);
    const char* Vpb = (const char*)(Vt + (size_t)bh * 65536);
    const ushort* QpA = Qh + ((size_t)bh * 1024 + q0 + l15) * 64;
    const ushort* QpB = QpA + 16 * 64;

    const int qrowA = q0 + l15;
    const size_t mbaseA = (((size_t)(b << 10) + qrowA) << 10) + g * 8;
    const int*   mA = mask + mbaseA;
    const int*   mB = mA + 16384;          // +16 q rows
    const float* gA = gp + mbaseA;
    const float* gB = gA + 16384;

    const short8 qa0 = *(const short8*)(QpA + g * 8);
    const short8 qa1 = *(const short8*)(QpA + 32 + g * 8);
    const short8 qb0 = *(const short8*)(QpB + g * 8);
    const short8 qb1 = *(const short8*)(QpB + 32 + g * 8);

    // staging: LDS row p holds K global row gk(p) (sigma perm), V row p (id).
    const int cb = (lane & 7) << 4;
    const int rA = wave * 8 + (lane >> 3);
    const int rB = rA + 32;
    const int gkA = (rA & 3) + 4 * ((rA >> 4) & 1) + 8 * ((rA >> 2) & 3) + 32 * (rA >> 5);
    const int gkB = (rB & 3) + 4 * ((rB >> 4) & 1) + 8 * ((rB >> 2) & 3) + 32 * (rB >> 5);
    const int okA = gkA * 128 + (cb ^ ((rA & 7) << 4));
    const int okB = gkB * 128 + (cb ^ ((rB & 7) << 4));
    const int ovA = rA * 2048 + (cb ^ ((rA & 7) << 4));
    const int ovB = rB * 2048 + (cb ^ ((rB & 7) << 4));

    const int sw = (l15 & 7) << 4;
    const int c0 = (g * 16) ^ sw;
    const int c1 = (64 + g * 16) ^ sw;

    f32x4 otA[4], otB[4];
    #pragma unroll
    for (int t = 0; t < 4; ++t) {
        otA[t] = (f32x4){0.f, 0.f, 0.f, 0.f};
        otB[t] = (f32x4){0.f, 0.f, 0.f, 0.f};
    }
    float lsA = 0.f, lsB = 0.f;

    // prologue: tile 0 -> buf 0
    gl16(Kpb + okA, &kv[0][0][wave * 512]);
    gl16(Kpb + okB, &kv[0][0][(4 + wave) * 512]);
    gl16(Vpb + ovA, &kv[0][1][wave * 512]);
    gl16(Vpb + ovB, &kv[0][1][(4 + wave) * 512]);
    __syncthreads();

    for (int t = 0; t < 16; ++t) {
        const int cur = t & 1;
        // mask/gprob for THIS tile (issued first; QK covers their latency)
        int   mmA[16], mmB[16];
        float gvA[16], gvB[16];
        ld16i(mA + t * 64, mmA);
        ld16f(gA + t * 64, gvA);
        ld16i(mB + t * 64, mmB);
        ld16f(gB + t * 64, gvB);

        if (t < 15) {
            const char* kp = Kpb + (size_t)(t + 1) * 8192;
            const char* vp = Vpb + (size_t)(t + 1) * 128;
            gl16(kp + okA, &kv[cur ^ 1][0][wave * 512]);
            gl16(kp + okB, &kv[cur ^ 1][0][(4 + wave) * 512]);
            gl16(vp + ovA, &kv[cur ^ 1][1][wave * 512]);
            gl16(vp + ovB, &kv[cur ^ 1][1][(4 + wave) * 512]);
        }
        const char* kbuf = (const char*)&kv[cur][0][0];
        const char* vbuf = (const char*)&kv[cur][1][0];

        // QK^T (swapped) for both Q-frags; K-frag regs reused across frags.
        f32x4 sA[4], sB[4];
        #pragma unroll
        for (int t4 = 0; t4 < 4; ++t4) {
            const char* ka = kbuf + (t4 * 16 + l15) * 128;
            short8 k0f = *(const short8*)(ka + c0);
            short8 k1f = *(const short8*)(ka + c1);
            f32x4 za = (f32x4){0.f, 0.f, 0.f, 0.f};
            za = mfma16(k0f, qa0, za);
            za = mfma16(k1f, qa1, za);
            sA[t4] = za;
            f32x4 zb = (f32x4){0.f, 0.f, 0.f, 0.f};
            zb = mfma16(k0f, qb0, zb);
            zb = mfma16(k1f, qb1, zb);
            sB[t4] = zb;
        }

        const int dqA = qrowA - t * 64 - g * 8;          // diag offset, frag A
        const int dqB = dqA + 16;                        // frag B rows are +16

        union { uint4 u; short8 s; } paA0, paA1, paB0, paB1;
        softmax_direct(mmA, gvA, dqA, sA, lsA, paA0.u, paA1.u);
        softmax_direct(mmB, gvB, dqB, sB, lsB, paB0.u, paB1.u);

        // PV for both frags; V-frag regs reused across frags.
        #pragma unroll
        for (int td = 0; td < 4; ++td) {
            const char* va = vbuf + (td * 16 + l15) * 128;
            short8 v0 = *(const short8*)(va + c0);
            short8 v1 = *(const short8*)(va + c1);
            otA[td] = mfma16(v0, paA0.s, otA[td]);
            otA[td] = mfma16(v1, paA1.s, otA[td]);
            otB[td] = mfma16(v0, paB0.s, otB[td]);
            otB[td] = mfma16(v1, paB1.s, otB[td]);
        }
        __syncthreads();
    }

    lsA += __shfl_xor(lsA, 16, 64);
    lsA += __shfl_xor(lsA, 32, 64);
    lsB += __shfl_xor(lsB, 16, 64);
    lsB += __shfl_xor(lsB, 32, 64);
    const float invA = 1.0f / lsA;
    const float invB = 1.0f / lsB;

    ushort* xpA = xo + ((size_t)bh * 1024 + q0 + l15) * 64;
    ushort* xpB = xpA + 16 * 64;
    #pragma unroll
    for (int td = 0; td < 4; ++td) {
        uint2 oa, ob;
        oa.x = cvtpk(otA[td][0] * invA, otA[td][1] * invA);
        oa.y = cvtpk(otA[td][2] * invA, otA[td][3] * invA);
        ob.x = cvtpk(otB[td][0] * invB, otB[td][1] * invB);
        ob.y = cvtpk(otB[td][2] * invB, otB[td][3] * invB);
        *(uint2*)(xpA + td * 16 + g * 4) = oa;
        *(uint2*)(xpB + td * 16 + g * 4) = ob;
    }
}

// ---------------------------------------------------------------------------
extern "C" void kernel_launch(void* const* d_in, const int* in_sizes, int n_in,
                              void* d_out, int out_size, void* d_ws, size_t ws_size,
                              hipStream_t stream)
{
    const float* query = (const float*)d_in[0];
    const float* key   = (const float*)d_in[1];
    const float* value = (const float*)d_in[2];
    const float* gprob = (const float*)d_in[3];
    const float* Wq    = (const float*)d_in[4];
    const float* Wk    = (const float*)d_in[5];
    const float* Wv    = (const float*)d_in[6];
    const float* Wh    = (const float*)d_in[7];
    const float* bh    = (const float*)d_in[8];
    const int*   mask  = (const int*)d_in[9];
    float* out = (float*)d_out;

    ushort* ws = (ushort*)d_ws;
    const size_t HS = (size_t)64 * 65536;   // 4,194,304
    ushort* q_ws = ws;
    ushort* k_ws = ws + HS;
    ushort* vT   = ws + 2 * HS;
    ushort* qb   = ws + 5 * HS;
    ushort* kb   = ws + 6 * HS;
    ushort* vb   = ws + 7 * HS;
    ushort* wqb  = ws + 8 * HS;
    ushort* wkb  = wqb + 262144;
    ushort* wvb  = wkb + 262144;
    ushort* whb  = wvb + 262144;
    ushort* x_ws = qb;                      // alias: qb dead after gemm3

    prep<<<13312, 256, 0, stream>>>(query, key, value, Wq, Wk, Wv, Wh,
                                    qb, kb, vb, wqb, wkb, wvb, whb);
    gemm3<<<dim3(64, 4, 3), 256, 0, stream>>>(qb, kb, vb, wqb, wkb, wvb,
                                              q_ws, k_ws, vT);
    attn<<<512, 256, 0, stream>>>(q_ws, k_ws, vT, mask, gprob, x_ws);
    gemm_o<<<dim3(64, 4), 256, 0, stream>>>(x_ws, whb, bh, out);
}

// Round 12
// 101.692 us; speedup vs baseline: 1.2746x; 1.2746x over previous
//
#include <hip/hip_runtime.h>
#include <hip/hip_bf16.h>
#include <cstdint>

// B=8, S=1024, D=512, H=8, DK=64. All-bf16 MFMA pipeline with
// global_load_lds staging and XOR-swizzled LDS (swizzle on SOURCE + READ).
// R12 = exact restore of the best measured configuration (R5, 101.8us).

typedef __attribute__((ext_vector_type(8))) short short8;
typedef __attribute__((ext_vector_type(4))) float f32x4;

__device__ __forceinline__ ushort f2bf(float x) {
    union { __hip_bfloat16 h; ushort u; } v;
    v.h = __float2bfloat16(x);
    return v.u;
}
__device__ __forceinline__ float bf2f(ushort u) {
    union { uint u; float f; } v; v.u = ((uint)u) << 16; return v.f;
}
__device__ __forceinline__ uint cvtpk(float lo, float hi) {
    uint r;
    asm("v_cvt_pk_bf16_f32 %0, %1, %2" : "=v"(r) : "v"(lo), "v"(hi));
    return r;
}
__device__ __forceinline__ f32x4 mfma16(short8 a, short8 b, f32x4 c) {
    return __builtin_amdgcn_mfma_f32_16x16x32_bf16(a, b, c, 0, 0, 0);
}
// async global->LDS, 16B per lane. LDS dest = wave-uniform base + lane*16.
__device__ __forceinline__ void gl16(const void* g, const void* l) {
    __builtin_amdgcn_global_load_lds(
        (const __attribute__((address_space(1))) uint32_t*)(uintptr_t)g,
        (__attribute__((address_space(3))) uint32_t*)(uint32_t)(uintptr_t)l,
        16, 0, 0);
}

// ---------------------------------------------------------------------------
// prep: [0,8192)   gm[b][q][k] = allowed ? bf16(gprob) : -1.0
//       [8192,20480) convert query/key/value fp32 -> bf16 flat [8192][512]
//       [20480,21504) convert Wq,Wk,Wv,Wh fp32 -> bf16 [512][512]
// ---------------------------------------------------------------------------
__global__ __launch_bounds__(256)
void prep(const float* __restrict__ q, const float* __restrict__ k,
          const float* __restrict__ v,
          const float* __restrict__ wq, const float* __restrict__ wk,
          const float* __restrict__ wv, const float* __restrict__ wh,
          const int* __restrict__ mask, const float* __restrict__ gp,
          ushort* __restrict__ qb, ushort* __restrict__ kb,
          ushort* __restrict__ vb,
          ushort* __restrict__ wqb, ushort* __restrict__ wkb,
          ushort* __restrict__ wvb, ushort* __restrict__ whb,
          ushort* __restrict__ gmb)
{
    const int bid = blockIdx.x, tid = threadIdx.x;
    if (bid < 8192) {
        size_t i = ((size_t)bid * 256 + tid) * 4;
        int4 m = *(const int4*)(mask + i);
        float4 gg = *(const float4*)(gp + i);
        int kk = (int)(i & 1023), qq = (int)((i >> 10) & 1023);
        uint u01 = cvtpk(gg.x, gg.y), u23 = cvtpk(gg.z, gg.w);
        ushort4 o;
        o.x = (m.x != 0 || qq == kk + 0) ? (ushort)(u01 & 0xffff) : (ushort)0xBF80;
        o.y = (m.y != 0 || qq == kk + 1) ? (ushort)(u01 >> 16)    : (ushort)0xBF80;
        o.z = (m.z != 0 || qq == kk + 2) ? (ushort)(u23 & 0xffff) : (ushort)0xBF80;
        o.w = (m.w != 0 || qq == kk + 3) ? (ushort)(u23 >> 16)    : (ushort)0xBF80;
        *(ushort4*)(gmb + i) = o;
    } else if (bid < 20480) {
        size_t id = ((size_t)(bid - 8192) * 256 + tid) * 4;
        int t = (int)(id >> 22);
        size_t off = id & 4194303;
        const float* s = (t == 0) ? q : (t == 1) ? k : v;
        ushort* d = (t == 0) ? qb : (t == 1) ? kb : vb;
        float4 x = *(const float4*)(s + off);
        uint2 o; o.x = cvtpk(x.x, x.y); o.y = cvtpk(x.z, x.w);
        *(uint2*)(d + off) = o;
    } else {
        size_t id = ((size_t)(bid - 20480) * 256 + tid) * 4;
        int t = (int)(id >> 18);
        size_t off = id & 262143;
        const float* s = (t == 0) ? wq : (t == 1) ? wk : (t == 2) ? wv : wh;
        ushort* d = (t == 0) ? wqb : (t == 1) ? wkb : (t == 2) ? wvb : whb;
        float4 x = *(const float4*)(s + off);
        uint2 o; o.x = cvtpk(x.x, x.y); o.y = cvtpk(x.z, x.w);
        *(uint2*)(d + off) = o;
    }
}

// ---------------------------------------------------------------------------
// QKV GEMM, bf16 x bf16, global_load_lds staging, BK=64, 128x128 tile.
// z=0: q_ws = (qb @ Wq^T) * (0.125*log2e), head layout; z=1: k_ws; z=2: vT.
// LDS rows 128B, XOR swizzle f(r)=(r&7)<<4 applied at SOURCE and READ.
// ---------------------------------------------------------------------------
__global__ __launch_bounds__(256, 2)
void gemm3(const ushort* __restrict__ qb, const ushort* __restrict__ kb,
           const ushort* __restrict__ vb,
           const ushort* __restrict__ Wqb, const ushort* __restrict__ Wkb,
           const ushort* __restrict__ Wvb,
           ushort* __restrict__ q_ws, ushort* __restrict__ k_ws,
           ushort* __restrict__ vT)
{
    __shared__ __attribute__((aligned(16))) ushort As[8192];
    __shared__ __attribute__((aligned(16))) ushort Bs[8192];

    const int z = blockIdx.z;
    const ushort* A = (z == 0) ? qb : (z == 1) ? kb : Wvb;
    const ushort* B = (z == 0) ? Wqb : (z == 1) ? Wkb : vb;
    const int mt = (z == 2) ? blockIdx.y : blockIdx.x;
    const int nt = (z == 2) ? blockIdx.x : blockIdx.y;
    const int m0 = mt * 128, n0 = nt * 128;
    const int tid = threadIdx.x, lane = tid & 63, wave = tid >> 6;
    const int l15 = lane & 15, g = lane >> 4;
    const int wm = wave >> 1, wn = wave & 1;

    const int cb = (lane & 7) << 4;
    int soff[4];
    #pragma unroll
    for (int it = 0; it < 4; ++it) {
        int r = (it * 4 + wave) * 8 + (lane >> 3);
        soff[it] = r * 1024 + (cb ^ ((r & 7) << 4));
    }
    const char* Ab = (const char*)A + (size_t)m0 * 1024;
    const char* Bb = (const char*)B + (size_t)n0 * 1024;

    const int sw = (l15 & 7) << 4;
    const int c0 = (g * 16) ^ sw;
    const int c1 = (64 + g * 16) ^ sw;

    f32x4 acc[4][4];
    #pragma unroll
    for (int i = 0; i < 4; ++i)
        #pragma unroll
        for (int j = 0; j < 4; ++j) acc[i][j] = (f32x4){0.f, 0.f, 0.f, 0.f};

    for (int ks = 0; ks < 8; ++ks) {
        const int kof = ks * 128;
        #pragma unroll
        for (int it = 0; it < 4; ++it) {
            gl16(Ab + soff[it] + kof, (const char*)As + (it * 4 + wave) * 1024);
            gl16(Bb + soff[it] + kof, (const char*)Bs + (it * 4 + wave) * 1024);
        }
        __syncthreads();
        #pragma unroll
        for (int kk = 0; kk < 2; ++kk) {
            const int cc = kk ? c1 : c0;
            short8 af[4], bf[4];
            #pragma unroll
            for (int i = 0; i < 4; ++i)
                af[i] = *(const short8*)((const char*)As + (wm * 64 + i * 16 + l15) * 128 + cc);
            #pragma unroll
            for (int j = 0; j < 4; ++j)
                bf[j] = *(const short8*)((const char*)Bs + (wn * 64 + j * 16 + l15) * 128 + cc);
            #pragma unroll
            for (int i = 0; i < 4; ++i)
                #pragma unroll
                for (int j = 0; j < 4; ++j)
                    acc[i][j] = mfma16(af[i], bf[j], acc[i][j]);
        }
        __syncthreads();
    }

    #pragma unroll
    for (int i = 0; i < 4; ++i) {
        #pragma unroll
        for (int j = 0; j < 4; ++j) {
            #pragma unroll
            for (int r = 0; r < 4; ++r) {
                int mm = m0 + wm * 64 + i * 16 + g * 4 + r;
                int nn = n0 + wn * 64 + j * 16 + l15;
                float val = acc[i][j][r];
                if (z == 0) {
                    val *= 0.18033688f;   // 1/sqrt(64) * log2(e) folded into Q
                    int b = mm >> 10, s = mm & 1023, h = nn >> 6, dk = nn & 63;
                    q_ws[((((size_t)(b * 8 + h)) << 10) + s) * 64 + dk] = f2bf(val);
                } else if (z == 1) {
                    int b = mm >> 10, s = mm & 1023, h = nn >> 6, dk = nn & 63;
                    k_ws[((((size_t)(b * 8 + h)) << 10) + s) * 64 + dk] = f2bf(val);
                } else {
                    int h = mm >> 6, d = mm & 63, b = nn >> 10, s = nn & 1023;
                    vT[(((size_t)(b * 8 + h) * 64 + d) << 10) + s] = f2bf(val);
                }
            }
        }
    }
}

// ---------------------------------------------------------------------------
// Out projection: out[m][n] = x_ws @ Wh^T + bias (f32 out).
// ---------------------------------------------------------------------------
__global__ __launch_bounds__(256, 2)
void gemm_o(const ushort* __restrict__ Xh, const ushort* __restrict__ Whb,
            const float* __restrict__ bias, float* __restrict__ out)
{
    __shared__ __attribute__((aligned(16))) ushort As[8192];
    __shared__ __attribute__((aligned(16))) ushort Bs[8192];

    const int m0 = blockIdx.x * 128, n0 = blockIdx.y * 128;
    const int tid = threadIdx.x, lane = tid & 63, wave = tid >> 6;
    const int l15 = lane & 15, g = lane >> 4;
    const int wm = wave >> 1, wn = wave & 1;
    const int bb = m0 >> 10, s0 = m0 & 1023;

    const int cb = (lane & 7) << 4;
    int aoff[4], boff[4];
    #pragma unroll
    for (int it = 0; it < 4; ++it) {
        int r = (it * 4 + wave) * 8 + (lane >> 3);
        int swz = cb ^ ((r & 7) << 4);
        aoff[it] = ((bb * 8) * 1024 + s0 + r) * 128 + swz;  // +ks*131072
        boff[it] = (n0 + r) * 1024 + swz;                   // +ks*128
    }
    const int sw = (l15 & 7) << 4;
    const int c0 = (g * 16) ^ sw;
    const int c1 = (64 + g * 16) ^ sw;

    f32x4 acc[4][4];
    #pragma unroll
    for (int i = 0; i < 4; ++i)
        #pragma unroll
        for (int j = 0; j < 4; ++j) acc[i][j] = (f32x4){0.f, 0.f, 0.f, 0.f};

    for (int ks = 0; ks < 8; ++ks) {
        #pragma unroll
        for (int it = 0; it < 4; ++it) {
            gl16((const char*)Xh + aoff[it] + ks * 131072,
                 (const char*)As + (it * 4 + wave) * 1024);
            gl16((const char*)Whb + boff[it] + ks * 128,
                 (const char*)Bs + (it * 4 + wave) * 1024);
        }
        __syncthreads();
        #pragma unroll
        for (int kk = 0; kk < 2; ++kk) {
            const int cc = kk ? c1 : c0;
            short8 af[4], bf[4];
            #pragma unroll
            for (int i = 0; i < 4; ++i)
                af[i] = *(const short8*)((const char*)As + (wm * 64 + i * 16 + l15) * 128 + cc);
            #pragma unroll
            for (int j = 0; j < 4; ++j)
                bf[j] = *(const short8*)((const char*)Bs + (wn * 64 + j * 16 + l15) * 128 + cc);
            #pragma unroll
            for (int i = 0; i < 4; ++i)
                #pragma unroll
                for (int j = 0; j < 4; ++j)
                    acc[i][j] = mfma16(af[i], bf[j], acc[i][j]);
        }
        __syncthreads();
    }

    float bv[4];
    #pragma unroll
    for (int j = 0; j < 4; ++j) bv[j] = bias[n0 + wn * 64 + j * 16 + l15];

    #pragma unroll
    for (int i = 0; i < 4; ++i)
        #pragma unroll
        for (int j = 0; j < 4; ++j)
            #pragma unroll
            for (int r = 0; r < 4; ++r) {
                int mm = m0 + wm * 64 + i * 16 + g * 4 + r;
                int nn = n0 + wn * 64 + j * 16 + l15;
                out[(size_t)mm * 512 + nn] = acc[i][j][r] + bv[j];
            }
}

// ---------------------------------------------------------------------------
// MFMA flash attention v3 (R5-exact): 4 waves x 32 q-rows = 128 q / block.
// Grid 512 (w = qt*64 + bh; XCD = bh%8). K/V staged via global_load_lds
// (sigma row-perm + XOR swizzle on per-lane SOURCE), double-buffered.
// NO online max: Q pre-scaled by 0.125*log2e; masked -> -1e9 -> exp2 == 0.
// ---------------------------------------------------------------------------
__global__ __launch_bounds__(256, 2)
void attn(const ushort* __restrict__ Qh, const ushort* __restrict__ Kh,
          const ushort* __restrict__ Vt, const ushort* __restrict__ gm,
          ushort* __restrict__ xo)
{
    __shared__ __attribute__((aligned(16))) ushort kv[2][2][4096];

    const int w = blockIdx.x;
    const int bh = w & 63, qt = w >> 6;
    const int tid = threadIdx.x, wave = tid >> 6, lane = tid & 63;
    const int l15 = lane & 15, g = lane >> 4;
    const int q0 = qt * 128 + wave * 32;      // this wave: q0..q0+31 (2 frags)
    const int b = bh >> 3;

    const char* Kpb = (const char*)(Kh + (size_t)bh * 65536);
    const char* Vpb = (const char*)(Vt + (size_t)bh * 65536);
    const ushort* QpA = Qh + ((size_t)bh * 1024 + q0 + l15) * 64;
    const ushort* QpB = QpA + 16 * 64;
    const ushort* gmpA = gm + ((size_t)b * 1024 + q0 + l15) * 1024;
    const ushort* gmpB = gmpA + 16 * 1024;

    const short8 qa0 = *(const short8*)(QpA + g * 8);
    const short8 qa1 = *(const short8*)(QpA + 32 + g * 8);
    const short8 qb0 = *(const short8*)(QpB + g * 8);
    const short8 qb1 = *(const short8*)(QpB + 32 + g * 8);

    // staging: LDS row p holds K global row gk(p) (sigma perm), V row p (id).
    const int cb = (lane & 7) << 4;
    const int rA = wave * 8 + (lane >> 3);
    const int rB = rA + 32;
    const int gkA = (rA & 3) + 4 * ((rA >> 4) & 1) + 8 * ((rA >> 2) & 3) + 32 * (rA >> 5);
    const int gkB = (rB & 3) + 4 * ((rB >> 4) & 1) + 8 * ((rB >> 2) & 3) + 32 * (rB >> 5);
    const int okA = gkA * 128 + (cb ^ ((rA & 7) << 4));
    const int okB = gkB * 128 + (cb ^ ((rB & 7) << 4));
    const int ovA = rA * 2048 + (cb ^ ((rA & 7) << 4));
    const int ovB = rB * 2048 + (cb ^ ((rB & 7) << 4));

    const int sw = (l15 & 7) << 4;
    const int c0 = (g * 16) ^ sw;
    const int c1 = (64 + g * 16) ^ sw;

    f32x4 otA[4], otB[4];
    #pragma unroll
    for (int t = 0; t < 4; ++t) {
        otA[t] = (f32x4){0.f, 0.f, 0.f, 0.f};
        otB[t] = (f32x4){0.f, 0.f, 0.f, 0.f};
    }
    float lsA = 0.f, lsB = 0.f;

    // prologue: tile 0 -> buf 0; gm tile 0 -> regs
    gl16(Kpb + okA, &kv[0][0][wave * 512]);
    gl16(Kpb + okB, &kv[0][0][(4 + wave) * 512]);
    gl16(Vpb + ovA, &kv[0][1][wave * 512]);
    gl16(Vpb + ovB, &kv[0][1][(4 + wave) * 512]);
    short8 gcA0 = *(const short8*)(gmpA + g * 8);
    short8 gcA1 = *(const short8*)(gmpA + 32 + g * 8);
    short8 gcB0 = *(const short8*)(gmpB + g * 8);
    short8 gcB1 = *(const short8*)(gmpB + 32 + g * 8);
    __syncthreads();

    for (int t = 0; t < 16; ++t) {
        const int cur = t & 1;
        short8 gnA0, gnA1, gnB0, gnB1;
        if (t < 15) {
            const char* kp = Kpb + (size_t)(t + 1) * 8192;
            const char* vp = Vpb + (size_t)(t + 1) * 128;
            gl16(kp + okA, &kv[cur ^ 1][0][wave * 512]);
            gl16(kp + okB, &kv[cur ^ 1][0][(4 + wave) * 512]);
            gl16(vp + ovA, &kv[cur ^ 1][1][wave * 512]);
            gl16(vp + ovB, &kv[cur ^ 1][1][(4 + wave) * 512]);
            gnA0 = *(const short8*)(gmpA + (t + 1) * 64 + g * 8);
            gnA1 = *(const short8*)(gmpA + (t + 1) * 64 + 32 + g * 8);
            gnB0 = *(const short8*)(gmpB + (t + 1) * 64 + g * 8);
            gnB1 = *(const short8*)(gmpB + (t + 1) * 64 + 32 + g * 8);
        }
        const char* kbuf = (const char*)&kv[cur][0][0];
        const char* vbuf = (const char*)&kv[cur][1][0];

        // QK^T (swapped) for both Q-frags; K-frag regs reused across frags.
        f32x4 sA[4], sB[4];
        #pragma unroll
        for (int t4 = 0; t4 < 4; ++t4) {
            const char* ka = kbuf + (t4 * 16 + l15) * 128;
            short8 k0f = *(const short8*)(ka + c0);
            short8 k1f = *(const short8*)(ka + c1);
            f32x4 za = (f32x4){0.f, 0.f, 0.f, 0.f};
            za = mfma16(k0f, qa0, za);
            za = mfma16(k1f, qa1, za);
            sA[t4] = za;
            f32x4 zb = (f32x4){0.f, 0.f, 0.f, 0.f};
            zb = mfma16(k0f, qb0, zb);
            zb = mfma16(k1f, qb1, zb);
            sB[t4] = zb;
        }

        // softmax (no max-tracking): p = exp2(s) (masked -> -1e9 -> 0)
        union { uint4 u; short8 s; } paA0, paA1, paB0, paB1;
        {
            float p[16], gv[16];
            #pragma unroll
            for (int c = 0; c < 2; ++c) {
                const short8 gc = c ? gcA1 : gcA0;
                #pragma unroll
                for (int j = 0; j < 8; ++j) {
                    const int jj = c * 8 + j;
                    const int t4 = 2 * c + (j >> 2), r = j & 3;
                    float gvv = bf2f((ushort)gc[j]);
                    gv[jj] = gvv;
                    p[jj] = exp2f((gvv >= 0.f) ? sA[t4][r] : -1.0e9f);
                }
            }
            lsA += (((p[0] + p[1]) + (p[2] + p[3])) + ((p[4] + p[5]) + (p[6] + p[7])))
                 + (((p[8] + p[9]) + (p[10] + p[11])) + ((p[12] + p[13]) + (p[14] + p[15])));
            paA0.u.x = cvtpk(p[0] * gv[0],  p[1] * gv[1]);
            paA0.u.y = cvtpk(p[2] * gv[2],  p[3] * gv[3]);
            paA0.u.z = cvtpk(p[4] * gv[4],  p[5] * gv[5]);
            paA0.u.w = cvtpk(p[6] * gv[6],  p[7] * gv[7]);
            paA1.u.x = cvtpk(p[8] * gv[8],  p[9] * gv[9]);
            paA1.u.y = cvtpk(p[10] * gv[10], p[11] * gv[11]);
            paA1.u.z = cvtpk(p[12] * gv[12], p[13] * gv[13]);
            paA1.u.w = cvtpk(p[14] * gv[14], p[15] * gv[15]);
        }
        {
            float p[16], gv[16];
            #pragma unroll
            for (int c = 0; c < 2; ++c) {
                const short8 gc = c ? gcB1 : gcB0;
                #pragma unroll
                for (int j = 0; j < 8; ++j) {
                    const int jj = c * 8 + j;
                    const int t4 = 2 * c + (j >> 2), r = j & 3;
                    float gvv = bf2f((ushort)gc[j]);
                    gv[jj] = gvv;
                    p[jj] = exp2f((gvv >= 0.f) ? sB[t4][r] : -1.0e9f);
                }
            }
            lsB += (((p[0] + p[1]) + (p[2] + p[3])) + ((p[4] + p[5]) + (p[6] + p[7])))
                 + (((p[8] + p[9]) + (p[10] + p[11])) + ((p[12] + p[13]) + (p[14] + p[15])));
            paB0.u.x = cvtpk(p[0] * gv[0],  p[1] * gv[1]);
            paB0.u.y = cvtpk(p[2] * gv[2],  p[3] * gv[3]);
            paB0.u.z = cvtpk(p[4] * gv[4],  p[5] * gv[5]);
            paB0.u.w = cvtpk(p[6] * gv[6],  p[7] * gv[7]);
            paB1.u.x = cvtpk(p[8] * gv[8],  p[9] * gv[9]);
            paB1.u.y = cvtpk(p[10] * gv[10], p[11] * gv[11]);
            paB1.u.z = cvtpk(p[12] * gv[12], p[13] * gv[13]);
            paB1.u.w = cvtpk(p[14] * gv[14], p[15] * gv[15]);
        }

        // PV for both frags; V-frag regs reused across frags.
        #pragma unroll
        for (int td = 0; td < 4; ++td) {
            const char* va = vbuf + (td * 16 + l15) * 128;
            short8 v0 = *(const short8*)(va + c0);
            short8 v1 = *(const short8*)(va + c1);
            otA[td] = mfma16(v0, paA0.s, otA[td]);
            otA[td] = mfma16(v1, paA1.s, otA[td]);
            otB[td] = mfma16(v0, paB0.s, otB[td]);
            otB[td] = mfma16(v1, paB1.s, otB[td]);
        }
        __syncthreads();
        if (t < 15) { gcA0 = gnA0; gcA1 = gnA1; gcB0 = gnB0; gcB1 = gnB1; }
    }

    lsA += __shfl_xor(lsA, 16, 64);
    lsA += __shfl_xor(lsA, 32, 64);
    lsB += __shfl_xor(lsB, 16, 64);
    lsB += __shfl_xor(lsB, 32, 64);
    const float invA = 1.0f / lsA;
    const float invB = 1.0f / lsB;

    ushort* xpA = xo + ((size_t)bh * 1024 + q0 + l15) * 64;
    ushort* xpB = xpA + 16 * 64;
    #pragma unroll
    for (int td = 0; td < 4; ++td) {
        uint2 oa, ob;
        oa.x = cvtpk(otA[td][0] * invA, otA[td][1] * invA);
        oa.y = cvtpk(otA[td][2] * invA, otA[td][3] * invA);
        ob.x = cvtpk(otB[td][0] * invB, otB[td][1] * invB);
        ob.y = cvtpk(otB[td][2] * invB, otB[td][3] * invB);
        *(uint2*)(xpA + td * 16 + g * 4) = oa;
        *(uint2*)(xpB + td * 16 + g * 4) = ob;
    }
}

// ---------------------------------------------------------------------------
extern "C" void kernel_launch(void* const* d_in, const int* in_sizes, int n_in,
                              void* d_out, int out_size, void* d_ws, size_t ws_size,
                              hipStream_t stream)
{
    const float* query = (const float*)d_in[0];
    const float* key   = (const float*)d_in[1];
    const float* value = (const float*)d_in[2];
    const float* gprob = (const float*)d_in[3];
    const float* Wq    = (const float*)d_in[4];
    const float* Wk    = (const float*)d_in[5];
    const float* Wv    = (const float*)d_in[6];
    const float* Wh    = (const float*)d_in[7];
    const float* bh    = (const float*)d_in[8];
    const int*   mask  = (const int*)d_in[9];
    float* out = (float*)d_out;

    ushort* ws = (ushort*)d_ws;
    const size_t HS = (size_t)64 * 65536;   // 4,194,304
    ushort* q_ws = ws;
    ushort* k_ws = ws + HS;
    ushort* vT   = ws + 2 * HS;
    ushort* gmb  = ws + 3 * HS;             // 2*HS elems
    ushort* qb   = ws + 5 * HS;
    ushort* kb   = ws + 6 * HS;
    ushort* vb   = ws + 7 * HS;
    ushort* wqb  = ws + 8 * HS;
    ushort* wkb  = wqb + 262144;
    ushort* wvb  = wkb + 262144;
    ushort* whb  = wvb + 262144;
    ushort* x_ws = qb;                      // alias: qb dead after gemm3

    prep<<<21504, 256, 0, stream>>>(query, key, value, Wq, Wk, Wv, Wh,
                                    mask, gprob, qb, kb, vb,
                                    wqb, wkb, wvb, whb, gmb);
    gemm3<<<dim3(64, 4, 3), 256, 0, stream>>>(qb, kb, vb, wqb, wkb, wvb,
                                              q_ws, k_ws, vT);
    attn<<<512, 256, 0, stream>>>(q_ws, k_ws, vT, gmb, x_ws);
    gemm_o<<<dim3(64, 4), 256, 0, stream>>>(x_ws, whb, bh, out);
}

// Round 13
// 100.117 us; speedup vs baseline: 1.2946x; 1.0157x over previous
//
#include <hip/hip_runtime.h>
#include <hip/hip_bf16.h>
#include <cstdint>

// B=8, S=1024, D=512, H=8, DK=64. All-bf16 MFMA pipeline with
// global_load_lds staging and XOR-swizzled LDS (swizzle on SOURCE + READ).
// R13 = R12 (verified 101.7us) + attn grid re-decomposition so XCD = b:
// b = w&7, qt = (w>>3)&7, h = w>>6. gm rows (shared by 8 heads) and K/V
// (shared by 8 q-tiles) become XCD-local -> L2 hits instead of 8x HBM fills.

typedef __attribute__((ext_vector_type(8))) short short8;
typedef __attribute__((ext_vector_type(4))) float f32x4;

__device__ __forceinline__ ushort f2bf(float x) {
    union { __hip_bfloat16 h; ushort u; } v;
    v.h = __float2bfloat16(x);
    return v.u;
}
__device__ __forceinline__ float bf2f(ushort u) {
    union { uint u; float f; } v; v.u = ((uint)u) << 16; return v.f;
}
__device__ __forceinline__ uint cvtpk(float lo, float hi) {
    uint r;
    asm("v_cvt_pk_bf16_f32 %0, %1, %2" : "=v"(r) : "v"(lo), "v"(hi));
    return r;
}
__device__ __forceinline__ f32x4 mfma16(short8 a, short8 b, f32x4 c) {
    return __builtin_amdgcn_mfma_f32_16x16x32_bf16(a, b, c, 0, 0, 0);
}
// async global->LDS, 16B per lane. LDS dest = wave-uniform base + lane*16.
__device__ __forceinline__ void gl16(const void* g, const void* l) {
    __builtin_amdgcn_global_load_lds(
        (const __attribute__((address_space(1))) uint32_t*)(uintptr_t)g,
        (__attribute__((address_space(3))) uint32_t*)(uint32_t)(uintptr_t)l,
        16, 0, 0);
}

// ---------------------------------------------------------------------------
// prep: [0,8192)   gm[b][q][k] = allowed ? bf16(gprob) : -1.0
//       [8192,20480) convert query/key/value fp32 -> bf16 flat [8192][512]
//       [20480,21504) convert Wq,Wk,Wv,Wh fp32 -> bf16 [512][512]
// ---------------------------------------------------------------------------
__global__ __launch_bounds__(256)
void prep(const float* __restrict__ q, const float* __restrict__ k,
          const float* __restrict__ v,
          const float* __restrict__ wq, const float* __restrict__ wk,
          const float* __restrict__ wv, const float* __restrict__ wh,
          const int* __restrict__ mask, const float* __restrict__ gp,
          ushort* __restrict__ qb, ushort* __restrict__ kb,
          ushort* __restrict__ vb,
          ushort* __restrict__ wqb, ushort* __restrict__ wkb,
          ushort* __restrict__ wvb, ushort* __restrict__ whb,
          ushort* __restrict__ gmb)
{
    const int bid = blockIdx.x, tid = threadIdx.x;
    if (bid < 8192) {
        size_t i = ((size_t)bid * 256 + tid) * 4;
        int4 m = *(const int4*)(mask + i);
        float4 gg = *(const float4*)(gp + i);
        int kk = (int)(i & 1023), qq = (int)((i >> 10) & 1023);
        uint u01 = cvtpk(gg.x, gg.y), u23 = cvtpk(gg.z, gg.w);
        ushort4 o;
        o.x = (m.x != 0 || qq == kk + 0) ? (ushort)(u01 & 0xffff) : (ushort)0xBF80;
        o.y = (m.y != 0 || qq == kk + 1) ? (ushort)(u01 >> 16)    : (ushort)0xBF80;
        o.z = (m.z != 0 || qq == kk + 2) ? (ushort)(u23 & 0xffff) : (ushort)0xBF80;
        o.w = (m.w != 0 || qq == kk + 3) ? (ushort)(u23 >> 16)    : (ushort)0xBF80;
        *(ushort4*)(gmb + i) = o;
    } else if (bid < 20480) {
        size_t id = ((size_t)(bid - 8192) * 256 + tid) * 4;
        int t = (int)(id >> 22);
        size_t off = id & 4194303;
        const float* s = (t == 0) ? q : (t == 1) ? k : v;
        ushort* d = (t == 0) ? qb : (t == 1) ? kb : vb;
        float4 x = *(const float4*)(s + off);
        uint2 o; o.x = cvtpk(x.x, x.y); o.y = cvtpk(x.z, x.w);
        *(uint2*)(d + off) = o;
    } else {
        size_t id = ((size_t)(bid - 20480) * 256 + tid) * 4;
        int t = (int)(id >> 18);
        size_t off = id & 262143;
        const float* s = (t == 0) ? wq : (t == 1) ? wk : (t == 2) ? wv : wh;
        ushort* d = (t == 0) ? wqb : (t == 1) ? wkb : (t == 2) ? wvb : whb;
        float4 x = *(const float4*)(s + off);
        uint2 o; o.x = cvtpk(x.x, x.y); o.y = cvtpk(x.z, x.w);
        *(uint2*)(d + off) = o;
    }
}

// ---------------------------------------------------------------------------
// QKV GEMM, bf16 x bf16, global_load_lds staging, BK=64, 128x128 tile.
// z=0: q_ws = (qb @ Wq^T) * (0.125*log2e), head layout; z=1: k_ws; z=2: vT.
// LDS rows 128B, XOR swizzle f(r)=(r&7)<<4 applied at SOURCE and READ.
// ---------------------------------------------------------------------------
__global__ __launch_bounds__(256, 2)
void gemm3(const ushort* __restrict__ qb, const ushort* __restrict__ kb,
           const ushort* __restrict__ vb,
           const ushort* __restrict__ Wqb, const ushort* __restrict__ Wkb,
           const ushort* __restrict__ Wvb,
           ushort* __restrict__ q_ws, ushort* __restrict__ k_ws,
           ushort* __restrict__ vT)
{
    __shared__ __attribute__((aligned(16))) ushort As[8192];
    __shared__ __attribute__((aligned(16))) ushort Bs[8192];

    const int z = blockIdx.z;
    const ushort* A = (z == 0) ? qb : (z == 1) ? kb : Wvb;
    const ushort* B = (z == 0) ? Wqb : (z == 1) ? Wkb : vb;
    const int mt = (z == 2) ? blockIdx.y : blockIdx.x;
    const int nt = (z == 2) ? blockIdx.x : blockIdx.y;
    const int m0 = mt * 128, n0 = nt * 128;
    const int tid = threadIdx.x, lane = tid & 63, wave = tid >> 6;
    const int l15 = lane & 15, g = lane >> 4;
    const int wm = wave >> 1, wn = wave & 1;

    const int cb = (lane & 7) << 4;
    int soff[4];
    #pragma unroll
    for (int it = 0; it < 4; ++it) {
        int r = (it * 4 + wave) * 8 + (lane >> 3);
        soff[it] = r * 1024 + (cb ^ ((r & 7) << 4));
    }
    const char* Ab = (const char*)A + (size_t)m0 * 1024;
    const char* Bb = (const char*)B + (size_t)n0 * 1024;

    const int sw = (l15 & 7) << 4;
    const int c0 = (g * 16) ^ sw;
    const int c1 = (64 + g * 16) ^ sw;

    f32x4 acc[4][4];
    #pragma unroll
    for (int i = 0; i < 4; ++i)
        #pragma unroll
        for (int j = 0; j < 4; ++j) acc[i][j] = (f32x4){0.f, 0.f, 0.f, 0.f};

    for (int ks = 0; ks < 8; ++ks) {
        const int kof = ks * 128;
        #pragma unroll
        for (int it = 0; it < 4; ++it) {
            gl16(Ab + soff[it] + kof, (const char*)As + (it * 4 + wave) * 1024);
            gl16(Bb + soff[it] + kof, (const char*)Bs + (it * 4 + wave) * 1024);
        }
        __syncthreads();
        #pragma unroll
        for (int kk = 0; kk < 2; ++kk) {
            const int cc = kk ? c1 : c0;
            short8 af[4], bf[4];
            #pragma unroll
            for (int i = 0; i < 4; ++i)
                af[i] = *(const short8*)((const char*)As + (wm * 64 + i * 16 + l15) * 128 + cc);
            #pragma unroll
            for (int j = 0; j < 4; ++j)
                bf[j] = *(const short8*)((const char*)Bs + (wn * 64 + j * 16 + l15) * 128 + cc);
            #pragma unroll
            for (int i = 0; i < 4; ++i)
                #pragma unroll
                for (int j = 0; j < 4; ++j)
                    acc[i][j] = mfma16(af[i], bf[j], acc[i][j]);
        }
        __syncthreads();
    }

    #pragma unroll
    for (int i = 0; i < 4; ++i) {
        #pragma unroll
        for (int j = 0; j < 4; ++j) {
            #pragma unroll
            for (int r = 0; r < 4; ++r) {
                int mm = m0 + wm * 64 + i * 16 + g * 4 + r;
                int nn = n0 + wn * 64 + j * 16 + l15;
                float val = acc[i][j][r];
                if (z == 0) {
                    val *= 0.18033688f;   // 1/sqrt(64) * log2(e) folded into Q
                    int b = mm >> 10, s = mm & 1023, h = nn >> 6, dk = nn & 63;
                    q_ws[((((size_t)(b * 8 + h)) << 10) + s) * 64 + dk] = f2bf(val);
                } else if (z == 1) {
                    int b = mm >> 10, s = mm & 1023, h = nn >> 6, dk = nn & 63;
                    k_ws[((((size_t)(b * 8 + h)) << 10) + s) * 64 + dk] = f2bf(val);
                } else {
                    int h = mm >> 6, d = mm & 63, b = nn >> 10, s = nn & 1023;
                    vT[(((size_t)(b * 8 + h) * 64 + d) << 10) + s] = f2bf(val);
                }
            }
        }
    }
}

// ---------------------------------------------------------------------------
// Out projection: out[m][n] = x_ws @ Wh^T + bias (f32 out).
// ---------------------------------------------------------------------------
__global__ __launch_bounds__(256, 2)
void gemm_o(const ushort* __restrict__ Xh, const ushort* __restrict__ Whb,
            const float* __restrict__ bias, float* __restrict__ out)
{
    __shared__ __attribute__((aligned(16))) ushort As[8192];
    __shared__ __attribute__((aligned(16))) ushort Bs[8192];

    const int m0 = blockIdx.x * 128, n0 = blockIdx.y * 128;
    const int tid = threadIdx.x, lane = tid & 63, wave = tid >> 6;
    const int l15 = lane & 15, g = lane >> 4;
    const int wm = wave >> 1, wn = wave & 1;
    const int bb = m0 >> 10, s0 = m0 & 1023;

    const int cb = (lane & 7) << 4;
    int aoff[4], boff[4];
    #pragma unroll
    for (int it = 0; it < 4; ++it) {
        int r = (it * 4 + wave) * 8 + (lane >> 3);
        int swz = cb ^ ((r & 7) << 4);
        aoff[it] = ((bb * 8) * 1024 + s0 + r) * 128 + swz;  // +ks*131072
        boff[it] = (n0 + r) * 1024 + swz;                   // +ks*128
    }
    const int sw = (l15 & 7) << 4;
    const int c0 = (g * 16) ^ sw;
    const int c1 = (64 + g * 16) ^ sw;

    f32x4 acc[4][4];
    #pragma unroll
    for (int i = 0; i < 4; ++i)
        #pragma unroll
        for (int j = 0; j < 4; ++j) acc[i][j] = (f32x4){0.f, 0.f, 0.f, 0.f};

    for (int ks = 0; ks < 8; ++ks) {
        #pragma unroll
        for (int it = 0; it < 4; ++it) {
            gl16((const char*)Xh + aoff[it] + ks * 131072,
                 (const char*)As + (it * 4 + wave) * 1024);
            gl16((const char*)Whb + boff[it] + ks * 128,
                 (const char*)Bs + (it * 4 + wave) * 1024);
        }
        __syncthreads();
        #pragma unroll
        for (int kk = 0; kk < 2; ++kk) {
            const int cc = kk ? c1 : c0;
            short8 af[4], bf[4];
            #pragma unroll
            for (int i = 0; i < 4; ++i)
                af[i] = *(const short8*)((const char*)As + (wm * 64 + i * 16 + l15) * 128 + cc);
            #pragma unroll
            for (int j = 0; j < 4; ++j)
                bf[j] = *(const short8*)((const char*)Bs + (wn * 64 + j * 16 + l15) * 128 + cc);
            #pragma unroll
            for (int i = 0; i < 4; ++i)
                #pragma unroll
                for (int j = 0; j < 4; ++j)
                    acc[i][j] = mfma16(af[i], bf[j], acc[i][j]);
        }
        __syncthreads();
    }

    float bv[4];
    #pragma unroll
    for (int j = 0; j < 4; ++j) bv[j] = bias[n0 + wn * 64 + j * 16 + l15];

    #pragma unroll
    for (int i = 0; i < 4; ++i)
        #pragma unroll
        for (int j = 0; j < 4; ++j)
            #pragma unroll
            for (int r = 0; r < 4; ++r) {
                int mm = m0 + wm * 64 + i * 16 + g * 4 + r;
                int nn = n0 + wn * 64 + j * 16 + l15;
                out[(size_t)mm * 512 + nn] = acc[i][j][r] + bv[j];
            }
}

// ---------------------------------------------------------------------------
// MFMA flash attention (R5 structure): 4 waves x 32 q-rows = 128 q / block.
// Grid 512. R13 decomposition: b = w&7 (XCD), qt = (w>>3)&7, h = w>>6 —
// each XCD owns one batch; gm (shared by 8 h) and K/V (shared by 8 qt)
// are XCD-local. K/V staged via global_load_lds (sigma row-perm + XOR
// swizzle on per-lane SOURCE), double-buffered. NO online max.
// ---------------------------------------------------------------------------
__global__ __launch_bounds__(256, 2)
void attn(const ushort* __restrict__ Qh, const ushort* __restrict__ Kh,
          const ushort* __restrict__ Vt, const ushort* __restrict__ gm,
          ushort* __restrict__ xo)
{
    __shared__ __attribute__((aligned(16))) ushort kv[2][2][4096];

    const int w = blockIdx.x;
    const int b  = w & 7;                 // XCD id
    const int qt = (w >> 3) & 7;
    const int h  = w >> 6;
    const int bh = b * 8 + h;
    const int tid = threadIdx.x, wave = tid >> 6, lane = tid & 63;
    const int l15 = lane & 15, g = lane >> 4;
    const int q0 = qt * 128 + wave * 32;      // this wave: q0..q0+31 (2 frags)

    const char* Kpb = (const char*)(Kh + (size_t)bh * 65536);
    const char* Vpb = (const char*)(Vt + (size_t)bh * 65536);
    const ushort* QpA = Qh + ((size_t)bh * 1024 + q0 + l15) * 64;
    const ushort* QpB = QpA + 16 * 64;
    const ushort* gmpA = gm + ((size_t)b * 1024 + q0 + l15) * 1024;
    const ushort* gmpB = gmpA + 16 * 1024;

    const short8 qa0 = *(const short8*)(QpA + g * 8);
    const short8 qa1 = *(const short8*)(QpA + 32 + g * 8);
    const short8 qb0 = *(const short8*)(QpB + g * 8);
    const short8 qb1 = *(const short8*)(QpB + 32 + g * 8);

    // staging: LDS row p holds K global row gk(p) (sigma perm), V row p (id).
    const int cb = (lane & 7) << 4;
    const int rA = wave * 8 + (lane >> 3);
    const int rB = rA + 32;
    const int gkA = (rA & 3) + 4 * ((rA >> 4) & 1) + 8 * ((rA >> 2) & 3) + 32 * (rA >> 5);
    const int gkB = (rB & 3) + 4 * ((rB >> 4) & 1) + 8 * ((rB >> 2) & 3) + 32 * (rB >> 5);
    const int okA = gkA * 128 + (cb ^ ((rA & 7) << 4));
    const int okB = gkB * 128 + (cb ^ ((rB & 7) << 4));
    const int ovA = rA * 2048 + (cb ^ ((rA & 7) << 4));
    const int ovB = rB * 2048 + (cb ^ ((rB & 7) << 4));

    const int sw = (l15 & 7) << 4;
    const int c0 = (g * 16) ^ sw;
    const int c1 = (64 + g * 16) ^ sw;

    f32x4 otA[4], otB[4];
    #pragma unroll
    for (int t = 0; t < 4; ++t) {
        otA[t] = (f32x4){0.f, 0.f, 0.f, 0.f};
        otB[t] = (f32x4){0.f, 0.f, 0.f, 0.f};
    }
    float lsA = 0.f, lsB = 0.f;

    // prologue: tile 0 -> buf 0; gm tile 0 -> regs
    gl16(Kpb + okA, &kv[0][0][wave * 512]);
    gl16(Kpb + okB, &kv[0][0][(4 + wave) * 512]);
    gl16(Vpb + ovA, &kv[0][1][wave * 512]);
    gl16(Vpb + ovB, &kv[0][1][(4 + wave) * 512]);
    short8 gcA0 = *(const short8*)(gmpA + g * 8);
    short8 gcA1 = *(const short8*)(gmpA + 32 + g * 8);
    short8 gcB0 = *(const short8*)(gmpB + g * 8);
    short8 gcB1 = *(const short8*)(gmpB + 32 + g * 8);
    __syncthreads();

    for (int t = 0; t < 16; ++t) {
        const int cur = t & 1;
        short8 gnA0, gnA1, gnB0, gnB1;
        if (t < 15) {
            const char* kp = Kpb + (size_t)(t + 1) * 8192;
            const char* vp = Vpb + (size_t)(t + 1) * 128;
            gl16(kp + okA, &kv[cur ^ 1][0][wave * 512]);
            gl16(kp + okB, &kv[cur ^ 1][0][(4 + wave) * 512]);
            gl16(vp + ovA, &kv[cur ^ 1][1][wave * 512]);
            gl16(vp + ovB, &kv[cur ^ 1][1][(4 + wave) * 512]);
            gnA0 = *(const short8*)(gmpA + (t + 1) * 64 + g * 8);
            gnA1 = *(const short8*)(gmpA + (t + 1) * 64 + 32 + g * 8);
            gnB0 = *(const short8*)(gmpB + (t + 1) * 64 + g * 8);
            gnB1 = *(const short8*)(gmpB + (t + 1) * 64 + 32 + g * 8);
        }
        const char* kbuf = (const char*)&kv[cur][0][0];
        const char* vbuf = (const char*)&kv[cur][1][0];

        // QK^T (swapped) for both Q-frags; K-frag regs reused across frags.
        f32x4 sA[4], sB[4];
        #pragma unroll
        for (int t4 = 0; t4 < 4; ++t4) {
            const char* ka = kbuf + (t4 * 16 + l15) * 128;
            short8 k0f = *(const short8*)(ka + c0);
            short8 k1f = *(const short8*)(ka + c1);
            f32x4 za = (f32x4){0.f, 0.f, 0.f, 0.f};
            za = mfma16(k0f, qa0, za);
            za = mfma16(k1f, qa1, za);
            sA[t4] = za;
            f32x4 zb = (f32x4){0.f, 0.f, 0.f, 0.f};
            zb = mfma16(k0f, qb0, zb);
            zb = mfma16(k1f, qb1, zb);
            sB[t4] = zb;
        }

        // softmax (no max-tracking): p = exp2(s) (masked -> -1e9 -> 0)
        union { uint4 u; short8 s; } paA0, paA1, paB0, paB1;
        {
            float p[16], gv[16];
            #pragma unroll
            for (int c = 0; c < 2; ++c) {
                const short8 gc = c ? gcA1 : gcA0;
                #pragma unroll
                for (int j = 0; j < 8; ++j) {
                    const int jj = c * 8 + j;
                    const int t4 = 2 * c + (j >> 2), r = j & 3;
                    float gvv = bf2f((ushort)gc[j]);
                    gv[jj] = gvv;
                    p[jj] = exp2f((gvv >= 0.f) ? sA[t4][r] : -1.0e9f);
                }
            }
            lsA += (((p[0] + p[1]) + (p[2] + p[3])) + ((p[4] + p[5]) + (p[6] + p[7])))
                 + (((p[8] + p[9]) + (p[10] + p[11])) + ((p[12] + p[13]) + (p[14] + p[15])));
            paA0.u.x = cvtpk(p[0] * gv[0],  p[1] * gv[1]);
            paA0.u.y = cvtpk(p[2] * gv[2],  p[3] * gv[3]);
            paA0.u.z = cvtpk(p[4] * gv[4],  p[5] * gv[5]);
            paA0.u.w = cvtpk(p[6] * gv[6],  p[7] * gv[7]);
            paA1.u.x = cvtpk(p[8] * gv[8],  p[9] * gv[9]);
            paA1.u.y = cvtpk(p[10] * gv[10], p[11] * gv[11]);
            paA1.u.z = cvtpk(p[12] * gv[12], p[13] * gv[13]);
            paA1.u.w = cvtpk(p[14] * gv[14], p[15] * gv[15]);
        }
        {
            float p[16], gv[16];
            #pragma unroll
            for (int c = 0; c < 2; ++c) {
                const short8 gc = c ? gcB1 : gcB0;
                #pragma unroll
                for (int j = 0; j < 8; ++j) {
                    const int jj = c * 8 + j;
                    const int t4 = 2 * c + (j >> 2), r = j & 3;
                    float gvv = bf2f((ushort)gc[j]);
                    gv[jj] = gvv;
                    p[jj] = exp2f((gvv >= 0.f) ? sB[t4][r] : -1.0e9f);
                }
            }
            lsB += (((p[0] + p[1]) + (p[2] + p[3])) + ((p[4] + p[5]) + (p[6] + p[7])))
                 + (((p[8] + p[9]) + (p[10] + p[11])) + ((p[12] + p[13]) + (p[14] + p[15])));
            paB0.u.x = cvtpk(p[0] * gv[0],  p[1] * gv[1]);
            paB0.u.y = cvtpk(p[2] * gv[2],  p[3] * gv[3]);
            paB0.u.z = cvtpk(p[4] * gv[4],  p[5] * gv[5]);
            paB0.u.w = cvtpk(p[6] * gv[6],  p[7] * gv[7]);
            paB1.u.x = cvtpk(p[8] * gv[8],  p[9] * gv[9]);
            paB1.u.y = cvtpk(p[10] * gv[10], p[11] * gv[11]);
            paB1.u.z = cvtpk(p[12] * gv[12], p[13] * gv[13]);
            paB1.u.w = cvtpk(p[14] * gv[14], p[15] * gv[15]);
        }

        // PV for both frags; V-frag regs reused across frags.
        #pragma unroll
        for (int td = 0; td < 4; ++td) {
            const char* va = vbuf + (td * 16 + l15) * 128;
            short8 v0 = *(const short8*)(va + c0);
            short8 v1 = *(const short8*)(va + c1);
            otA[td] = mfma16(v0, paA0.s, otA[td]);
            otA[td] = mfma16(v1, paA1.s, otA[td]);
            otB[td] = mfma16(v0, paB0.s, otB[td]);
            otB[td] = mfma16(v1, paB1.s, otB[td]);
        }
        __syncthreads();
        if (t < 15) { gcA0 = gnA0; gcA1 = gnA1; gcB0 = gnB0; gcB1 = gnB1; }
    }

    lsA += __shfl_xor(lsA, 16, 64);
    lsA += __shfl_xor(lsA, 32, 64);
    lsB += __shfl_xor(lsB, 16, 64);
    lsB += __shfl_xor(lsB, 32, 64);
    const float invA = 1.0f / lsA;
    const float invB = 1.0f / lsB;

    ushort* xpA = xo + ((size_t)bh * 1024 + q0 + l15) * 64;
    ushort* xpB = xpA + 16 * 64;
    #pragma unroll
    for (int td = 0; td < 4; ++td) {
        uint2 oa, ob;
        oa.x = cvtpk(otA[td][0] * invA, otA[td][1] * invA);
        oa.y = cvtpk(otA[td][2] * invA, otA[td][3] * invA);
        ob.x = cvtpk(otB[td][0] * invB, otB[td][1] * invB);
        ob.y = cvtpk(otB[td][2] * invB, otB[td][3] * invB);
        *(uint2*)(xpA + td * 16 + g * 4) = oa;
        *(uint2*)(xpB + td * 16 + g * 4) = ob;
    }
}

// ---------------------------------------------------------------------------
extern "C" void kernel_launch(void* const* d_in, const int* in_sizes, int n_in,
                              void* d_out, int out_size, void* d_ws, size_t ws_size,
                              hipStream_t stream)
{
    const float* query = (const float*)d_in[0];
    const float* key   = (const float*)d_in[1];
    const float* value = (const float*)d_in[2];
    const float* gprob = (const float*)d_in[3];
    const float* Wq    = (const float*)d_in[4];
    const float* Wk    = (const float*)d_in[5];
    const float* Wv    = (const float*)d_in[6];
    const float* Wh    = (const float*)d_in[7];
    const float* bh    = (const float*)d_in[8];
    const int*   mask  = (const int*)d_in[9];
    float* out = (float*)d_out;

    ushort* ws = (ushort*)d_ws;
    const size_t HS = (size_t)64 * 65536;   // 4,194,304
    ushort* q_ws = ws;
    ushort* k_ws = ws + HS;
    ushort* vT   = ws + 2 * HS;
    ushort* gmb  = ws + 3 * HS;             // 2*HS elems
    ushort* qb   = ws + 5 * HS;
    ushort* kb   = ws + 6 * HS;
    ushort* vb   = ws + 7 * HS;
    ushort* wqb  = ws + 8 * HS;
    ushort* wkb  = wqb + 262144;
    ushort* wvb  = wkb + 262144;
    ushort* whb  = wvb + 262144;
    ushort* x_ws = qb;                      // alias: qb dead after gemm3

    prep<<<21504, 256, 0, stream>>>(query, key, value, Wq, Wk, Wv, Wh,
                                    mask, gprob, qb, kb, vb,
                                    wqb, wkb, wvb, whb, gmb);
    gemm3<<<dim3(64, 4, 3), 256, 0, stream>>>(qb, kb, vb, wqb, wkb, wvb,
                                              q_ws, k_ws, vT);
    attn<<<512, 256, 0, stream>>>(q_ws, k_ws, vT, gmb, x_ws);
    gemm_o<<<dim3(64, 4), 256, 0, stream>>>(x_ws, whb, bh, out);
}

// Round 14
// 97.243 us; speedup vs baseline: 1.3329x; 1.0296x over previous
//
#include <hip/hip_runtime.h>
#include <hip/hip_bf16.h>
#include <cstdint>

// B=8, S=1024, D=512, H=8, DK=64. All-bf16 MFMA pipeline.
// R14 = R13 + T15 att[2] double-pipeline in attn: QK(t+1) computed BEFORE
// softmax(t) (3-buffer LDS rotation, 2-ahead staging) so MFMA + stage
// latency hide under the softmax VALU phase. Math identical to R13.

typedef __attribute__((ext_vector_type(8))) short short8;
typedef __attribute__((ext_vector_type(4))) float f32x4;

__device__ __forceinline__ ushort f2bf(float x) {
    union { __hip_bfloat16 h; ushort u; } v;
    v.h = __float2bfloat16(x);
    return v.u;
}
__device__ __forceinline__ float bf2f(ushort u) {
    union { uint u; float f; } v; v.u = ((uint)u) << 16; return v.f;
}
__device__ __forceinline__ uint cvtpk(float lo, float hi) {
    uint r;
    asm("v_cvt_pk_bf16_f32 %0, %1, %2" : "=v"(r) : "v"(lo), "v"(hi));
    return r;
}
__device__ __forceinline__ f32x4 mfma16(short8 a, short8 b, f32x4 c) {
    return __builtin_amdgcn_mfma_f32_16x16x32_bf16(a, b, c, 0, 0, 0);
}
// async global->LDS, 16B per lane. LDS dest = wave-uniform base + lane*16.
__device__ __forceinline__ void gl16(const void* g, const void* l) {
    __builtin_amdgcn_global_load_lds(
        (const __attribute__((address_space(1))) uint32_t*)(uintptr_t)g,
        (__attribute__((address_space(3))) uint32_t*)(uint32_t)(uintptr_t)l,
        16, 0, 0);
}

// ---------------------------------------------------------------------------
// prep: [0,8192)   gm[b][q][k] = allowed ? bf16(gprob) : -1.0
//       [8192,20480) convert query/key/value fp32 -> bf16 flat [8192][512]
//       [20480,21504) convert Wq,Wk,Wv,Wh fp32 -> bf16 [512][512]
// ---------------------------------------------------------------------------
__global__ __launch_bounds__(256)
void prep(const float* __restrict__ q, const float* __restrict__ k,
          const float* __restrict__ v,
          const float* __restrict__ wq, const float* __restrict__ wk,
          const float* __restrict__ wv, const float* __restrict__ wh,
          const int* __restrict__ mask, const float* __restrict__ gp,
          ushort* __restrict__ qb, ushort* __restrict__ kb,
          ushort* __restrict__ vb,
          ushort* __restrict__ wqb, ushort* __restrict__ wkb,
          ushort* __restrict__ wvb, ushort* __restrict__ whb,
          ushort* __restrict__ gmb)
{
    const int bid = blockIdx.x, tid = threadIdx.x;
    if (bid < 8192) {
        size_t i = ((size_t)bid * 256 + tid) * 4;
        int4 m = *(const int4*)(mask + i);
        float4 gg = *(const float4*)(gp + i);
        int kk = (int)(i & 1023), qq = (int)((i >> 10) & 1023);
        uint u01 = cvtpk(gg.x, gg.y), u23 = cvtpk(gg.z, gg.w);
        ushort4 o;
        o.x = (m.x != 0 || qq == kk + 0) ? (ushort)(u01 & 0xffff) : (ushort)0xBF80;
        o.y = (m.y != 0 || qq == kk + 1) ? (ushort)(u01 >> 16)    : (ushort)0xBF80;
        o.z = (m.z != 0 || qq == kk + 2) ? (ushort)(u23 & 0xffff) : (ushort)0xBF80;
        o.w = (m.w != 0 || qq == kk + 3) ? (ushort)(u23 >> 16)    : (ushort)0xBF80;
        *(ushort4*)(gmb + i) = o;
    } else if (bid < 20480) {
        size_t id = ((size_t)(bid - 8192) * 256 + tid) * 4;
        int t = (int)(id >> 22);
        size_t off = id & 4194303;
        const float* s = (t == 0) ? q : (t == 1) ? k : v;
        ushort* d = (t == 0) ? qb : (t == 1) ? kb : vb;
        float4 x = *(const float4*)(s + off);
        uint2 o; o.x = cvtpk(x.x, x.y); o.y = cvtpk(x.z, x.w);
        *(uint2*)(d + off) = o;
    } else {
        size_t id = ((size_t)(bid - 20480) * 256 + tid) * 4;
        int t = (int)(id >> 18);
        size_t off = id & 262143;
        const float* s = (t == 0) ? wq : (t == 1) ? wk : (t == 2) ? wv : wh;
        ushort* d = (t == 0) ? wqb : (t == 1) ? wkb : (t == 2) ? wvb : whb;
        float4 x = *(const float4*)(s + off);
        uint2 o; o.x = cvtpk(x.x, x.y); o.y = cvtpk(x.z, x.w);
        *(uint2*)(d + off) = o;
    }
}

// ---------------------------------------------------------------------------
// QKV GEMM (unchanged, known-good)
// ---------------------------------------------------------------------------
__global__ __launch_bounds__(256, 2)
void gemm3(const ushort* __restrict__ qb, const ushort* __restrict__ kb,
           const ushort* __restrict__ vb,
           const ushort* __restrict__ Wqb, const ushort* __restrict__ Wkb,
           const ushort* __restrict__ Wvb,
           ushort* __restrict__ q_ws, ushort* __restrict__ k_ws,
           ushort* __restrict__ vT)
{
    __shared__ __attribute__((aligned(16))) ushort As[8192];
    __shared__ __attribute__((aligned(16))) ushort Bs[8192];

    const int z = blockIdx.z;
    const ushort* A = (z == 0) ? qb : (z == 1) ? kb : Wvb;
    const ushort* B = (z == 0) ? Wqb : (z == 1) ? Wkb : vb;
    const int mt = (z == 2) ? blockIdx.y : blockIdx.x;
    const int nt = (z == 2) ? blockIdx.x : blockIdx.y;
    const int m0 = mt * 128, n0 = nt * 128;
    const int tid = threadIdx.x, lane = tid & 63, wave = tid >> 6;
    const int l15 = lane & 15, g = lane >> 4;
    const int wm = wave >> 1, wn = wave & 1;

    const int cb = (lane & 7) << 4;
    int soff[4];
    #pragma unroll
    for (int it = 0; it < 4; ++it) {
        int r = (it * 4 + wave) * 8 + (lane >> 3);
        soff[it] = r * 1024 + (cb ^ ((r & 7) << 4));
    }
    const char* Ab = (const char*)A + (size_t)m0 * 1024;
    const char* Bb = (const char*)B + (size_t)n0 * 1024;

    const int sw = (l15 & 7) << 4;
    const int c0 = (g * 16) ^ sw;
    const int c1 = (64 + g * 16) ^ sw;

    f32x4 acc[4][4];
    #pragma unroll
    for (int i = 0; i < 4; ++i)
        #pragma unroll
        for (int j = 0; j < 4; ++j) acc[i][j] = (f32x4){0.f, 0.f, 0.f, 0.f};

    for (int ks = 0; ks < 8; ++ks) {
        const int kof = ks * 128;
        #pragma unroll
        for (int it = 0; it < 4; ++it) {
            gl16(Ab + soff[it] + kof, (const char*)As + (it * 4 + wave) * 1024);
            gl16(Bb + soff[it] + kof, (const char*)Bs + (it * 4 + wave) * 1024);
        }
        __syncthreads();
        #pragma unroll
        for (int kk = 0; kk < 2; ++kk) {
            const int cc = kk ? c1 : c0;
            short8 af[4], bf[4];
            #pragma unroll
            for (int i = 0; i < 4; ++i)
                af[i] = *(const short8*)((const char*)As + (wm * 64 + i * 16 + l15) * 128 + cc);
            #pragma unroll
            for (int j = 0; j < 4; ++j)
                bf[j] = *(const short8*)((const char*)Bs + (wn * 64 + j * 16 + l15) * 128 + cc);
            #pragma unroll
            for (int i = 0; i < 4; ++i)
                #pragma unroll
                for (int j = 0; j < 4; ++j)
                    acc[i][j] = mfma16(af[i], bf[j], acc[i][j]);
        }
        __syncthreads();
    }

    #pragma unroll
    for (int i = 0; i < 4; ++i) {
        #pragma unroll
        for (int j = 0; j < 4; ++j) {
            #pragma unroll
            for (int r = 0; r < 4; ++r) {
                int mm = m0 + wm * 64 + i * 16 + g * 4 + r;
                int nn = n0 + wn * 64 + j * 16 + l15;
                float val = acc[i][j][r];
                if (z == 0) {
                    val *= 0.18033688f;   // 1/sqrt(64) * log2(e) folded into Q
                    int b = mm >> 10, s = mm & 1023, h = nn >> 6, dk = nn & 63;
                    q_ws[((((size_t)(b * 8 + h)) << 10) + s) * 64 + dk] = f2bf(val);
                } else if (z == 1) {
                    int b = mm >> 10, s = mm & 1023, h = nn >> 6, dk = nn & 63;
                    k_ws[((((size_t)(b * 8 + h)) << 10) + s) * 64 + dk] = f2bf(val);
                } else {
                    int h = mm >> 6, d = mm & 63, b = nn >> 10, s = nn & 1023;
                    vT[(((size_t)(b * 8 + h) * 64 + d) << 10) + s] = f2bf(val);
                }
            }
        }
    }
}

// ---------------------------------------------------------------------------
// Out projection (unchanged, known-good)
// ---------------------------------------------------------------------------
__global__ __launch_bounds__(256, 2)
void gemm_o(const ushort* __restrict__ Xh, const ushort* __restrict__ Whb,
            const float* __restrict__ bias, float* __restrict__ out)
{
    __shared__ __attribute__((aligned(16))) ushort As[8192];
    __shared__ __attribute__((aligned(16))) ushort Bs[8192];

    const int m0 = blockIdx.x * 128, n0 = blockIdx.y * 128;
    const int tid = threadIdx.x, lane = tid & 63, wave = tid >> 6;
    const int l15 = lane & 15, g = lane >> 4;
    const int wm = wave >> 1, wn = wave & 1;
    const int bb = m0 >> 10, s0 = m0 & 1023;

    const int cb = (lane & 7) << 4;
    int aoff[4], boff[4];
    #pragma unroll
    for (int it = 0; it < 4; ++it) {
        int r = (it * 4 + wave) * 8 + (lane >> 3);
        int swz = cb ^ ((r & 7) << 4);
        aoff[it] = ((bb * 8) * 1024 + s0 + r) * 128 + swz;  // +ks*131072
        boff[it] = (n0 + r) * 1024 + swz;                   // +ks*128
    }
    const int sw = (l15 & 7) << 4;
    const int c0 = (g * 16) ^ sw;
    const int c1 = (64 + g * 16) ^ sw;

    f32x4 acc[4][4];
    #pragma unroll
    for (int i = 0; i < 4; ++i)
        #pragma unroll
        for (int j = 0; j < 4; ++j) acc[i][j] = (f32x4){0.f, 0.f, 0.f, 0.f};

    for (int ks = 0; ks < 8; ++ks) {
        #pragma unroll
        for (int it = 0; it < 4; ++it) {
            gl16((const char*)Xh + aoff[it] + ks * 131072,
                 (const char*)As + (it * 4 + wave) * 1024);
            gl16((const char*)Whb + boff[it] + ks * 128,
                 (const char*)Bs + (it * 4 + wave) * 1024);
        }
        __syncthreads();
        #pragma unroll
        for (int kk = 0; kk < 2; ++kk) {
            const int cc = kk ? c1 : c0;
            short8 af[4], bf[4];
            #pragma unroll
            for (int i = 0; i < 4; ++i)
                af[i] = *(const short8*)((const char*)As + (wm * 64 + i * 16 + l15) * 128 + cc);
            #pragma unroll
            for (int j = 0; j < 4; ++j)
                bf[j] = *(const short8*)((const char*)Bs + (wn * 64 + j * 16 + l15) * 128 + cc);
            #pragma unroll
            for (int i = 0; i < 4; ++i)
                #pragma unroll
                for (int j = 0; j < 4; ++j)
                    acc[i][j] = mfma16(af[i], bf[j], acc[i][j]);
        }
        __syncthreads();
    }

    float bv[4];
    #pragma unroll
    for (int j = 0; j < 4; ++j) bv[j] = bias[n0 + wn * 64 + j * 16 + l15];

    #pragma unroll
    for (int i = 0; i < 4; ++i)
        #pragma unroll
        for (int j = 0; j < 4; ++j)
            #pragma unroll
            for (int r = 0; r < 4; ++r) {
                int mm = m0 + wm * 64 + i * 16 + g * 4 + r;
                int nn = n0 + wn * 64 + j * 16 + l15;
                out[(size_t)mm * 512 + nn] = acc[i][j][r] + bv[j];
            }
}

// ---------------------------------------------------------------------------
// attn v8 (T15 double-pipeline): per iteration —
//   [stage(t+2) -> buf[(t+2)%3]] [gm(t+1) loads] [QK(t+1) MFMA -> s_next]
//   [softmax(t) on s_prev : VALU — hides QK+stage latency] [PV(t)] [barrier]
// 3 LDS buffers (48 KB), score regs alternate sE/sO (static, macro-unrolled).
// Grid 512: b = w&7 (XCD), qt = (w>>3)&7, h = w>>6. NO online max.
// ---------------------------------------------------------------------------
__device__ __forceinline__ void softmax16(const short8 gc0, const short8 gc1,
                                          const f32x4 (&s4)[4], float& lsum,
                                          uint4& u0, uint4& u1)
{
    float p[16], gv[16];
    #pragma unroll
    for (int c = 0; c < 2; ++c) {
        const short8 gc = c ? gc1 : gc0;
        #pragma unroll
        for (int j = 0; j < 8; ++j) {
            const int jj = c * 8 + j;
            const int t4 = 2 * c + (j >> 2), r = j & 3;
            float gvv = bf2f((ushort)gc[j]);
            gv[jj] = gvv;
            p[jj] = exp2f((gvv >= 0.f) ? s4[t4][r] : -1.0e9f);
        }
    }
    lsum += (((p[0] + p[1]) + (p[2] + p[3])) + ((p[4] + p[5]) + (p[6] + p[7])))
          + (((p[8] + p[9]) + (p[10] + p[11])) + ((p[12] + p[13]) + (p[14] + p[15])));
    u0.x = cvtpk(p[0] * gv[0],  p[1] * gv[1]);
    u0.y = cvtpk(p[2] * gv[2],  p[3] * gv[3]);
    u0.z = cvtpk(p[4] * gv[4],  p[5] * gv[5]);
    u0.w = cvtpk(p[6] * gv[6],  p[7] * gv[7]);
    u1.x = cvtpk(p[8] * gv[8],  p[9] * gv[9]);
    u1.y = cvtpk(p[10] * gv[10], p[11] * gv[11]);
    u1.z = cvtpk(p[12] * gv[12], p[13] * gv[13]);
    u1.w = cvtpk(p[14] * gv[14], p[15] * gv[15]);
}

#define QKX(BUFN, SA, SB)                                                      \
    _Pragma("unroll")                                                          \
    for (int t4_ = 0; t4_ < 4; ++t4_) {                                        \
        const char* ka_ = (const char*)&kv[BUFN][0][0] + (t4_ * 16 + l15) * 128;\
        short8 k0_ = *(const short8*)(ka_ + c0);                               \
        short8 k1_ = *(const short8*)(ka_ + c1);                               \
        f32x4 za_ = (f32x4){0.f, 0.f, 0.f, 0.f};                               \
        za_ = mfma16(k0_, qa0, za_);                                           \
        za_ = mfma16(k1_, qa1, za_);                                           \
        SA[t4_] = za_;                                                         \
        f32x4 zb_ = (f32x4){0.f, 0.f, 0.f, 0.f};                               \
        zb_ = mfma16(k0_, qb0, zb_);                                           \
        zb_ = mfma16(k1_, qb1, zb_);                                           \
        SB[t4_] = zb_;                                                         \
    }

#define TILEX(T, CUR, NXT, STG, SPA, SPB, SNA, SNB)                            \
  do {                                                                         \
    if ((T) < 14) {                                                            \
        const char* kp_ = Kpb + (size_t)((T) + 2) * 8192;                      \
        const char* vp_ = Vpb + (size_t)((T) + 2) * 128;                       \
        gl16(kp_ + okA, &kv[STG][0][wave * 512]);                              \
        gl16(kp_ + okB, &kv[STG][0][(4 + wave) * 512]);                        \
        gl16(vp_ + ovA, &kv[STG][1][wave * 512]);                              \
        gl16(vp_ + ovB, &kv[STG][1][(4 + wave) * 512]);                        \
    }                                                                          \
    short8 gnA0, gnA1, gnB0, gnB1;                                             \
    if ((T) < 15) {                                                            \
        gnA0 = *(const short8*)(gmpA + ((T) + 1) * 64 + g * 8);                \
        gnA1 = *(const short8*)(gmpA + ((T) + 1) * 64 + 32 + g * 8);           \
        gnB0 = *(const short8*)(gmpB + ((T) + 1) * 64 + g * 8);                \
        gnB1 = *(const short8*)(gmpB + ((T) + 1) * 64 + 32 + g * 8);           \
        QKX(NXT, SNA, SNB);                                                    \
    }                                                                          \
    union { uint4 u; short8 s; } paA0_, paA1_, paB0_, paB1_;                   \
    softmax16(gcA0, gcA1, SPA, lsA, paA0_.u, paA1_.u);                         \
    softmax16(gcB0, gcB1, SPB, lsB, paB0_.u, paB1_.u);                         \
    _Pragma("unroll")                                                          \
    for (int td_ = 0; td_ < 4; ++td_) {                                        \
        const char* va_ = (const char*)&kv[CUR][1][0] + (td_ * 16 + l15) * 128;\
        short8 v0_ = *(const short8*)(va_ + c0);                               \
        short8 v1_ = *(const short8*)(va_ + c1);                               \
        otA[td_] = mfma16(v0_, paA0_.s, otA[td_]);                             \
        otA[td_] = mfma16(v1_, paA1_.s, otA[td_]);                             \
        otB[td_] = mfma16(v0_, paB0_.s, otB[td_]);                             \
        otB[td_] = mfma16(v1_, paB1_.s, otB[td_]);                             \
    }                                                                          \
    if ((T) < 15) {                                                            \
        __syncthreads();                                                       \
        gcA0 = gnA0; gcA1 = gnA1; gcB0 = gnB0; gcB1 = gnB1;                    \
    }                                                                          \
  } while (0)

__global__ __launch_bounds__(256, 2)
void attn(const ushort* __restrict__ Qh, const ushort* __restrict__ Kh,
          const ushort* __restrict__ Vt, const ushort* __restrict__ gm,
          ushort* __restrict__ xo)
{
    __shared__ __attribute__((aligned(16))) ushort kv[3][2][4096];   // 48 KB

    const int w = blockIdx.x;
    const int b  = w & 7;                 // XCD id
    const int qt = (w >> 3) & 7;
    const int h  = w >> 6;
    const int bh = b * 8 + h;
    const int tid = threadIdx.x, wave = tid >> 6, lane = tid & 63;
    const int l15 = lane & 15, g = lane >> 4;
    const int q0 = qt * 128 + wave * 32;      // this wave: q0..q0+31 (2 frags)

    const char* Kpb = (const char*)(Kh + (size_t)bh * 65536);
    const char* Vpb = (const char*)(Vt + (size_t)bh * 65536);
    const ushort* QpA = Qh + ((size_t)bh * 1024 + q0 + l15) * 64;
    const ushort* QpB = QpA + 16 * 64;
    const ushort* gmpA = gm + ((size_t)b * 1024 + q0 + l15) * 1024;
    const ushort* gmpB = gmpA + 16 * 1024;

    const short8 qa0 = *(const short8*)(QpA + g * 8);
    const short8 qa1 = *(const short8*)(QpA + 32 + g * 8);
    const short8 qb0 = *(const short8*)(QpB + g * 8);
    const short8 qb1 = *(const short8*)(QpB + 32 + g * 8);

    // staging: LDS row p holds K global row gk(p) (sigma perm), V row p (id).
    const int cb = (lane & 7) << 4;
    const int rA = wave * 8 + (lane >> 3);
    const int rB = rA + 32;
    const int gkA = (rA & 3) + 4 * ((rA >> 4) & 1) + 8 * ((rA >> 2) & 3) + 32 * (rA >> 5);
    const int gkB = (rB & 3) + 4 * ((rB >> 4) & 1) + 8 * ((rB >> 2) & 3) + 32 * (rB >> 5);
    const int okA = gkA * 128 + (cb ^ ((rA & 7) << 4));
    const int okB = gkB * 128 + (cb ^ ((rB & 7) << 4));
    const int ovA = rA * 2048 + (cb ^ ((rA & 7) << 4));
    const int ovB = rB * 2048 + (cb ^ ((rB & 7) << 4));

    const int sw = (l15 & 7) << 4;
    const int c0 = (g * 16) ^ sw;
    const int c1 = (64 + g * 16) ^ sw;

    f32x4 otA[4], otB[4];
    #pragma unroll
    for (int t = 0; t < 4; ++t) {
        otA[t] = (f32x4){0.f, 0.f, 0.f, 0.f};
        otB[t] = (f32x4){0.f, 0.f, 0.f, 0.f};
    }
    float lsA = 0.f, lsB = 0.f;
    f32x4 sEA[4], sEB[4], sOA[4], sOB[4];
    short8 gcA0, gcA1, gcB0, gcB1;

    // prologue: stage tiles 0,1 -> buf 0,1; gm(0) -> regs; QK(0) -> sE
    gl16(Kpb + okA, &kv[0][0][wave * 512]);
    gl16(Kpb + okB, &kv[0][0][(4 + wave) * 512]);
    gl16(Vpb + ovA, &kv[0][1][wave * 512]);
    gl16(Vpb + ovB, &kv[0][1][(4 + wave) * 512]);
    gl16(Kpb + 8192 + okA, &kv[1][0][wave * 512]);
    gl16(Kpb + 8192 + okB, &kv[1][0][(4 + wave) * 512]);
    gl16(Vpb + 128 + ovA, &kv[1][1][wave * 512]);
    gl16(Vpb + 128 + ovB, &kv[1][1][(4 + wave) * 512]);
    gcA0 = *(const short8*)(gmpA + g * 8);
    gcA1 = *(const short8*)(gmpA + 32 + g * 8);
    gcB0 = *(const short8*)(gmpB + g * 8);
    gcB1 = *(const short8*)(gmpB + 32 + g * 8);
    __syncthreads();
    QKX(0, sEA, sEB);

    TILEX(0,  0, 1, 2, sEA, sEB, sOA, sOB);
    TILEX(1,  1, 2, 0, sOA, sOB, sEA, sEB);
    TILEX(2,  2, 0, 1, sEA, sEB, sOA, sOB);
    TILEX(3,  0, 1, 2, sOA, sOB, sEA, sEB);
    TILEX(4,  1, 2, 0, sEA, sEB, sOA, sOB);
    TILEX(5,  2, 0, 1, sOA, sOB, sEA, sEB);
    TILEX(6,  0, 1, 2, sEA, sEB, sOA, sOB);
    TILEX(7,  1, 2, 0, sOA, sOB, sEA, sEB);
    TILEX(8,  2, 0, 1, sEA, sEB, sOA, sOB);
    TILEX(9,  0, 1, 2, sOA, sOB, sEA, sEB);
    TILEX(10, 1, 2, 0, sEA, sEB, sOA, sOB);
    TILEX(11, 2, 0, 1, sOA, sOB, sEA, sEB);
    TILEX(12, 0, 1, 2, sEA, sEB, sOA, sOB);
    TILEX(13, 1, 2, 0, sOA, sOB, sEA, sEB);
    TILEX(14, 2, 0, 1, sEA, sEB, sOA, sOB);
    TILEX(15, 0, 1, 2, sOA, sOB, sEA, sEB);

    lsA += __shfl_xor(lsA, 16, 64);
    lsA += __shfl_xor(lsA, 32, 64);
    lsB += __shfl_xor(lsB, 16, 64);
    lsB += __shfl_xor(lsB, 32, 64);
    const float invA = 1.0f / lsA;
    const float invB = 1.0f / lsB;

    ushort* xpA = xo + ((size_t)bh * 1024 + q0 + l15) * 64;
    ushort* xpB = xpA + 16 * 64;
    #pragma unroll
    for (int td = 0; td < 4; ++td) {
        uint2 oa, ob;
        oa.x = cvtpk(otA[td][0] * invA, otA[td][1] * invA);
        oa.y = cvtpk(otA[td][2] * invA, otA[td][3] * invA);
        ob.x = cvtpk(otB[td][0] * invB, otB[td][1] * invB);
        ob.y = cvtpk(otB[td][2] * invB, otB[td][3] * invB);
        *(uint2*)(xpA + td * 16 + g * 4) = oa;
        *(uint2*)(xpB + td * 16 + g * 4) = ob;
    }
}

// ---------------------------------------------------------------------------
extern "C" void kernel_launch(void* const* d_in, const int* in_sizes, int n_in,
                              void* d_out, int out_size, void* d_ws, size_t ws_size,
                              hipStream_t stream)
{
    const float* query = (const float*)d_in[0];
    const float* key   = (const float*)d_in[1];
    const float* value = (const float*)d_in[2];
    const float* gprob = (const float*)d_in[3];
    const float* Wq    = (const float*)d_in[4];
    const float* Wk    = (const float*)d_in[5];
    const float* Wv    = (const float*)d_in[6];
    const float* Wh    = (const float*)d_in[7];
    const float* bh    = (const float*)d_in[8];
    const int*   mask  = (const int*)d_in[9];
    float* out = (float*)d_out;

    ushort* ws = (ushort*)d_ws;
    const size_t HS = (size_t)64 * 65536;   // 4,194,304
    ushort* q_ws = ws;
    ushort* k_ws = ws + HS;
    ushort* vT   = ws + 2 * HS;
    ushort* gmb  = ws + 3 * HS;             // 2*HS elems
    ushort* qb   = ws + 5 * HS;
    ushort* kb   = ws + 6 * HS;
    ushort* vb   = ws + 7 * HS;
    ushort* wqb  = ws + 8 * HS;
    ushort* wkb  = wqb + 262144;
    ushort* wvb  = wkb + 262144;
    ushort* whb  = wvb + 262144;
    ushort* x_ws = qb;                      // alias: qb dead after gemm3

    prep<<<21504, 256, 0, stream>>>(query, key, value, Wq, Wk, Wv, Wh,
                                    mask, gprob, qb, kb, vb,
                                    wqb, wkb, wvb, whb, gmb);
    gemm3<<<dim3(64, 4, 3), 256, 0, stream>>>(qb, kb, vb, wqb, wkb, wvb,
                                              q_ws, k_ws, vT);
    attn<<<512, 256, 0, stream>>>(q_ws, k_ws, vT, gmb, x_ws);
    gemm_o<<<dim3(64, 4), 256, 0, stream>>>(x_ws, whb, bh, out);
}

// Round 15
// 95.305 us; speedup vs baseline: 1.3600x; 1.0203x over previous
//
#include <hip/hip_runtime.h>
#include <hip/hip_bf16.h>
#include <cstdint>

// B=8, S=1024, D=512, H=8, DK=64. All-bf16 MFMA pipeline.
// R15 = R14 (T15 double-pipeline attn, 97.2us) + T5 s_setprio(1) around the
// QK and PV MFMA clusters (T15's phase split gives the scheduler role
// diversity to arbitrate -> m191's +4-7% attn regime).

typedef __attribute__((ext_vector_type(8))) short short8;
typedef __attribute__((ext_vector_type(4))) float f32x4;

__device__ __forceinline__ ushort f2bf(float x) {
    union { __hip_bfloat16 h; ushort u; } v;
    v.h = __float2bfloat16(x);
    return v.u;
}
__device__ __forceinline__ float bf2f(ushort u) {
    union { uint u; float f; } v; v.u = ((uint)u) << 16; return v.f;
}
__device__ __forceinline__ uint cvtpk(float lo, float hi) {
    uint r;
    asm("v_cvt_pk_bf16_f32 %0, %1, %2" : "=v"(r) : "v"(lo), "v"(hi));
    return r;
}
__device__ __forceinline__ f32x4 mfma16(short8 a, short8 b, f32x4 c) {
    return __builtin_amdgcn_mfma_f32_16x16x32_bf16(a, b, c, 0, 0, 0);
}
// async global->LDS, 16B per lane. LDS dest = wave-uniform base + lane*16.
__device__ __forceinline__ void gl16(const void* g, const void* l) {
    __builtin_amdgcn_global_load_lds(
        (const __attribute__((address_space(1))) uint32_t*)(uintptr_t)g,
        (__attribute__((address_space(3))) uint32_t*)(uint32_t)(uintptr_t)l,
        16, 0, 0);
}

// ---------------------------------------------------------------------------
// prep: [0,8192)   gm[b][q][k] = allowed ? bf16(gprob) : -1.0
//       [8192,20480) convert query/key/value fp32 -> bf16 flat [8192][512]
//       [20480,21504) convert Wq,Wk,Wv,Wh fp32 -> bf16 [512][512]
// ---------------------------------------------------------------------------
__global__ __launch_bounds__(256)
void prep(const float* __restrict__ q, const float* __restrict__ k,
          const float* __restrict__ v,
          const float* __restrict__ wq, const float* __restrict__ wk,
          const float* __restrict__ wv, const float* __restrict__ wh,
          const int* __restrict__ mask, const float* __restrict__ gp,
          ushort* __restrict__ qb, ushort* __restrict__ kb,
          ushort* __restrict__ vb,
          ushort* __restrict__ wqb, ushort* __restrict__ wkb,
          ushort* __restrict__ wvb, ushort* __restrict__ whb,
          ushort* __restrict__ gmb)
{
    const int bid = blockIdx.x, tid = threadIdx.x;
    if (bid < 8192) {
        size_t i = ((size_t)bid * 256 + tid) * 4;
        int4 m = *(const int4*)(mask + i);
        float4 gg = *(const float4*)(gp + i);
        int kk = (int)(i & 1023), qq = (int)((i >> 10) & 1023);
        uint u01 = cvtpk(gg.x, gg.y), u23 = cvtpk(gg.z, gg.w);
        ushort4 o;
        o.x = (m.x != 0 || qq == kk + 0) ? (ushort)(u01 & 0xffff) : (ushort)0xBF80;
        o.y = (m.y != 0 || qq == kk + 1) ? (ushort)(u01 >> 16)    : (ushort)0xBF80;
        o.z = (m.z != 0 || qq == kk + 2) ? (ushort)(u23 & 0xffff) : (ushort)0xBF80;
        o.w = (m.w != 0 || qq == kk + 3) ? (ushort)(u23 >> 16)    : (ushort)0xBF80;
        *(ushort4*)(gmb + i) = o;
    } else if (bid < 20480) {
        size_t id = ((size_t)(bid - 8192) * 256 + tid) * 4;
        int t = (int)(id >> 22);
        size_t off = id & 4194303;
        const float* s = (t == 0) ? q : (t == 1) ? k : v;
        ushort* d = (t == 0) ? qb : (t == 1) ? kb : vb;
        float4 x = *(const float4*)(s + off);
        uint2 o; o.x = cvtpk(x.x, x.y); o.y = cvtpk(x.z, x.w);
        *(uint2*)(d + off) = o;
    } else {
        size_t id = ((size_t)(bid - 20480) * 256 + tid) * 4;
        int t = (int)(id >> 18);
        size_t off = id & 262143;
        const float* s = (t == 0) ? wq : (t == 1) ? wk : (t == 2) ? wv : wh;
        ushort* d = (t == 0) ? wqb : (t == 1) ? wkb : (t == 2) ? wvb : whb;
        float4 x = *(const float4*)(s + off);
        uint2 o; o.x = cvtpk(x.x, x.y); o.y = cvtpk(x.z, x.w);
        *(uint2*)(d + off) = o;
    }
}

// ---------------------------------------------------------------------------
// QKV GEMM (unchanged, known-good)
// ---------------------------------------------------------------------------
__global__ __launch_bounds__(256, 2)
void gemm3(const ushort* __restrict__ qb, const ushort* __restrict__ kb,
           const ushort* __restrict__ vb,
           const ushort* __restrict__ Wqb, const ushort* __restrict__ Wkb,
           const ushort* __restrict__ Wvb,
           ushort* __restrict__ q_ws, ushort* __restrict__ k_ws,
           ushort* __restrict__ vT)
{
    __shared__ __attribute__((aligned(16))) ushort As[8192];
    __shared__ __attribute__((aligned(16))) ushort Bs[8192];

    const int z = blockIdx.z;
    const ushort* A = (z == 0) ? qb : (z == 1) ? kb : Wvb;
    const ushort* B = (z == 0) ? Wqb : (z == 1) ? Wkb : vb;
    const int mt = (z == 2) ? blockIdx.y : blockIdx.x;
    const int nt = (z == 2) ? blockIdx.x : blockIdx.y;
    const int m0 = mt * 128, n0 = nt * 128;
    const int tid = threadIdx.x, lane = tid & 63, wave = tid >> 6;
    const int l15 = lane & 15, g = lane >> 4;
    const int wm = wave >> 1, wn = wave & 1;

    const int cb = (lane & 7) << 4;
    int soff[4];
    #pragma unroll
    for (int it = 0; it < 4; ++it) {
        int r = (it * 4 + wave) * 8 + (lane >> 3);
        soff[it] = r * 1024 + (cb ^ ((r & 7) << 4));
    }
    const char* Ab = (const char*)A + (size_t)m0 * 1024;
    const char* Bb = (const char*)B + (size_t)n0 * 1024;

    const int sw = (l15 & 7) << 4;
    const int c0 = (g * 16) ^ sw;
    const int c1 = (64 + g * 16) ^ sw;

    f32x4 acc[4][4];
    #pragma unroll
    for (int i = 0; i < 4; ++i)
        #pragma unroll
        for (int j = 0; j < 4; ++j) acc[i][j] = (f32x4){0.f, 0.f, 0.f, 0.f};

    for (int ks = 0; ks < 8; ++ks) {
        const int kof = ks * 128;
        #pragma unroll
        for (int it = 0; it < 4; ++it) {
            gl16(Ab + soff[it] + kof, (const char*)As + (it * 4 + wave) * 1024);
            gl16(Bb + soff[it] + kof, (const char*)Bs + (it * 4 + wave) * 1024);
        }
        __syncthreads();
        #pragma unroll
        for (int kk = 0; kk < 2; ++kk) {
            const int cc = kk ? c1 : c0;
            short8 af[4], bf[4];
            #pragma unroll
            for (int i = 0; i < 4; ++i)
                af[i] = *(const short8*)((const char*)As + (wm * 64 + i * 16 + l15) * 128 + cc);
            #pragma unroll
            for (int j = 0; j < 4; ++j)
                bf[j] = *(const short8*)((const char*)Bs + (wn * 64 + j * 16 + l15) * 128 + cc);
            #pragma unroll
            for (int i = 0; i < 4; ++i)
                #pragma unroll
                for (int j = 0; j < 4; ++j)
                    acc[i][j] = mfma16(af[i], bf[j], acc[i][j]);
        }
        __syncthreads();
    }

    #pragma unroll
    for (int i = 0; i < 4; ++i) {
        #pragma unroll
        for (int j = 0; j < 4; ++j) {
            #pragma unroll
            for (int r = 0; r < 4; ++r) {
                int mm = m0 + wm * 64 + i * 16 + g * 4 + r;
                int nn = n0 + wn * 64 + j * 16 + l15;
                float val = acc[i][j][r];
                if (z == 0) {
                    val *= 0.18033688f;   // 1/sqrt(64) * log2(e) folded into Q
                    int b = mm >> 10, s = mm & 1023, h = nn >> 6, dk = nn & 63;
                    q_ws[((((size_t)(b * 8 + h)) << 10) + s) * 64 + dk] = f2bf(val);
                } else if (z == 1) {
                    int b = mm >> 10, s = mm & 1023, h = nn >> 6, dk = nn & 63;
                    k_ws[((((size_t)(b * 8 + h)) << 10) + s) * 64 + dk] = f2bf(val);
                } else {
                    int h = mm >> 6, d = mm & 63, b = nn >> 10, s = nn & 1023;
                    vT[(((size_t)(b * 8 + h) * 64 + d) << 10) + s] = f2bf(val);
                }
            }
        }
    }
}

// ---------------------------------------------------------------------------
// Out projection (unchanged, known-good)
// ---------------------------------------------------------------------------
__global__ __launch_bounds__(256, 2)
void gemm_o(const ushort* __restrict__ Xh, const ushort* __restrict__ Whb,
            const float* __restrict__ bias, float* __restrict__ out)
{
    __shared__ __attribute__((aligned(16))) ushort As[8192];
    __shared__ __attribute__((aligned(16))) ushort Bs[8192];

    const int m0 = blockIdx.x * 128, n0 = blockIdx.y * 128;
    const int tid = threadIdx.x, lane = tid & 63, wave = tid >> 6;
    const int l15 = lane & 15, g = lane >> 4;
    const int wm = wave >> 1, wn = wave & 1;
    const int bb = m0 >> 10, s0 = m0 & 1023;

    const int cb = (lane & 7) << 4;
    int aoff[4], boff[4];
    #pragma unroll
    for (int it = 0; it < 4; ++it) {
        int r = (it * 4 + wave) * 8 + (lane >> 3);
        int swz = cb ^ ((r & 7) << 4);
        aoff[it] = ((bb * 8) * 1024 + s0 + r) * 128 + swz;  // +ks*131072
        boff[it] = (n0 + r) * 1024 + swz;                   // +ks*128
    }
    const int sw = (l15 & 7) << 4;
    const int c0 = (g * 16) ^ sw;
    const int c1 = (64 + g * 16) ^ sw;

    f32x4 acc[4][4];
    #pragma unroll
    for (int i = 0; i < 4; ++i)
        #pragma unroll
        for (int j = 0; j < 4; ++j) acc[i][j] = (f32x4){0.f, 0.f, 0.f, 0.f};

    for (int ks = 0; ks < 8; ++ks) {
        #pragma unroll
        for (int it = 0; it < 4; ++it) {
            gl16((const char*)Xh + aoff[it] + ks * 131072,
                 (const char*)As + (it * 4 + wave) * 1024);
            gl16((const char*)Whb + boff[it] + ks * 128,
                 (const char*)Bs + (it * 4 + wave) * 1024);
        }
        __syncthreads();
        #pragma unroll
        for (int kk = 0; kk < 2; ++kk) {
            const int cc = kk ? c1 : c0;
            short8 af[4], bf[4];
            #pragma unroll
            for (int i = 0; i < 4; ++i)
                af[i] = *(const short8*)((const char*)As + (wm * 64 + i * 16 + l15) * 128 + cc);
            #pragma unroll
            for (int j = 0; j < 4; ++j)
                bf[j] = *(const short8*)((const char*)Bs + (wn * 64 + j * 16 + l15) * 128 + cc);
            #pragma unroll
            for (int i = 0; i < 4; ++i)
                #pragma unroll
                for (int j = 0; j < 4; ++j)
                    acc[i][j] = mfma16(af[i], bf[j], acc[i][j]);
        }
        __syncthreads();
    }

    float bv[4];
    #pragma unroll
    for (int j = 0; j < 4; ++j) bv[j] = bias[n0 + wn * 64 + j * 16 + l15];

    #pragma unroll
    for (int i = 0; i < 4; ++i)
        #pragma unroll
        for (int j = 0; j < 4; ++j)
            #pragma unroll
            for (int r = 0; r < 4; ++r) {
                int mm = m0 + wm * 64 + i * 16 + g * 4 + r;
                int nn = n0 + wn * 64 + j * 16 + l15;
                out[(size_t)mm * 512 + nn] = acc[i][j][r] + bv[j];
            }
}

// ---------------------------------------------------------------------------
// attn v9 (T15 + T5): per iteration —
//   [stage(t+2)] [gm(t+1)] [setprio(1) QK(t+1) setprio(0)]
//   [softmax(t) VALU] [setprio(1) PV(t) setprio(0)] [barrier]
// 3 LDS buffers (48 KB), score regs alternate sE/sO (static, macro-unrolled).
// Grid 512: b = w&7 (XCD), qt = (w>>3)&7, h = w>>6. NO online max.
// ---------------------------------------------------------------------------
__device__ __forceinline__ void softmax16(const short8 gc0, const short8 gc1,
                                          const f32x4 (&s4)[4], float& lsum,
                                          uint4& u0, uint4& u1)
{
    float p[16], gv[16];
    #pragma unroll
    for (int c = 0; c < 2; ++c) {
        const short8 gc = c ? gc1 : gc0;
        #pragma unroll
        for (int j = 0; j < 8; ++j) {
            const int jj = c * 8 + j;
            const int t4 = 2 * c + (j >> 2), r = j & 3;
            float gvv = bf2f((ushort)gc[j]);
            gv[jj] = gvv;
            p[jj] = exp2f((gvv >= 0.f) ? s4[t4][r] : -1.0e9f);
        }
    }
    lsum += (((p[0] + p[1]) + (p[2] + p[3])) + ((p[4] + p[5]) + (p[6] + p[7])))
          + (((p[8] + p[9]) + (p[10] + p[11])) + ((p[12] + p[13]) + (p[14] + p[15])));
    u0.x = cvtpk(p[0] * gv[0],  p[1] * gv[1]);
    u0.y = cvtpk(p[2] * gv[2],  p[3] * gv[3]);
    u0.z = cvtpk(p[4] * gv[4],  p[5] * gv[5]);
    u0.w = cvtpk(p[6] * gv[6],  p[7] * gv[7]);
    u1.x = cvtpk(p[8] * gv[8],  p[9] * gv[9]);
    u1.y = cvtpk(p[10] * gv[10], p[11] * gv[11]);
    u1.z = cvtpk(p[12] * gv[12], p[13] * gv[13]);
    u1.w = cvtpk(p[14] * gv[14], p[15] * gv[15]);
}

#define QKX(BUFN, SA, SB)                                                      \
  do {                                                                         \
    __builtin_amdgcn_s_setprio(1);                                             \
    _Pragma("unroll")                                                          \
    for (int t4_ = 0; t4_ < 4; ++t4_) {                                        \
        const char* ka_ = (const char*)&kv[BUFN][0][0] + (t4_ * 16 + l15) * 128;\
        short8 k0_ = *(const short8*)(ka_ + c0);                               \
        short8 k1_ = *(const short8*)(ka_ + c1);                               \
        f32x4 za_ = (f32x4){0.f, 0.f, 0.f, 0.f};                               \
        za_ = mfma16(k0_, qa0, za_);                                           \
        za_ = mfma16(k1_, qa1, za_);                                           \
        SA[t4_] = za_;                                                         \
        f32x4 zb_ = (f32x4){0.f, 0.f, 0.f, 0.f};                               \
        zb_ = mfma16(k0_, qb0, zb_);                                           \
        zb_ = mfma16(k1_, qb1, zb_);                                           \
        SB[t4_] = zb_;                                                         \
    }                                                                          \
    __builtin_amdgcn_s_setprio(0);                                             \
  } while (0)

#define TILEX(T, CUR, NXT, STG, SPA, SPB, SNA, SNB)                            \
  do {                                                                         \
    if ((T) < 14) {                                                            \
        const char* kp_ = Kpb + (size_t)((T) + 2) * 8192;                      \
        const char* vp_ = Vpb + (size_t)((T) + 2) * 128;                       \
        gl16(kp_ + okA, &kv[STG][0][wave * 512]);                              \
        gl16(kp_ + okB, &kv[STG][0][(4 + wave) * 512]);                        \
        gl16(vp_ + ovA, &kv[STG][1][wave * 512]);                              \
        gl16(vp_ + ovB, &kv[STG][1][(4 + wave) * 512]);                        \
    }                                                                          \
    short8 gnA0, gnA1, gnB0, gnB1;                                             \
    if ((T) < 15) {                                                            \
        gnA0 = *(const short8*)(gmpA + ((T) + 1) * 64 + g * 8);                \
        gnA1 = *(const short8*)(gmpA + ((T) + 1) * 64 + 32 + g * 8);           \
        gnB0 = *(const short8*)(gmpB + ((T) + 1) * 64 + g * 8);                \
        gnB1 = *(const short8*)(gmpB + ((T) + 1) * 64 + 32 + g * 8);           \
        QKX(NXT, SNA, SNB);                                                    \
    }                                                                          \
    union { uint4 u; short8 s; } paA0_, paA1_, paB0_, paB1_;                   \
    softmax16(gcA0, gcA1, SPA, lsA, paA0_.u, paA1_.u);                         \
    softmax16(gcB0, gcB1, SPB, lsB, paB0_.u, paB1_.u);                         \
    __builtin_amdgcn_s_setprio(1);                                             \
    _Pragma("unroll")                                                          \
    for (int td_ = 0; td_ < 4; ++td_) {                                        \
        const char* va_ = (const char*)&kv[CUR][1][0] + (td_ * 16 + l15) * 128;\
        short8 v0_ = *(const short8*)(va_ + c0);                               \
        short8 v1_ = *(const short8*)(va_ + c1);                               \
        otA[td_] = mfma16(v0_, paA0_.s, otA[td_]);                             \
        otA[td_] = mfma16(v1_, paA1_.s, otA[td_]);                             \
        otB[td_] = mfma16(v0_, paB0_.s, otB[td_]);                             \
        otB[td_] = mfma16(v1_, paB1_.s, otB[td_]);                             \
    }                                                                          \
    __builtin_amdgcn_s_setprio(0);                                             \
    if ((T) < 15) {                                                            \
        __syncthreads();                                                       \
        gcA0 = gnA0; gcA1 = gnA1; gcB0 = gnB0; gcB1 = gnB1;                    \
    }                                                                          \
  } while (0)

__global__ __launch_bounds__(256, 2)
void attn(const ushort* __restrict__ Qh, const ushort* __restrict__ Kh,
          const ushort* __restrict__ Vt, const ushort* __restrict__ gm,
          ushort* __restrict__ xo)
{
    __shared__ __attribute__((aligned(16))) ushort kv[3][2][4096];   // 48 KB

    const int w = blockIdx.x;
    const int b  = w & 7;                 // XCD id
    const int qt = (w >> 3) & 7;
    const int h  = w >> 6;
    const int bh = b * 8 + h;
    const int tid = threadIdx.x, wave = tid >> 6, lane = tid & 63;
    const int l15 = lane & 15, g = lane >> 4;
    const int q0 = qt * 128 + wave * 32;      // this wave: q0..q0+31 (2 frags)

    const char* Kpb = (const char*)(Kh + (size_t)bh * 65536);
    const char* Vpb = (const char*)(Vt + (size_t)bh * 65536);
    const ushort* QpA = Qh + ((size_t)bh * 1024 + q0 + l15) * 64;
    const ushort* QpB = QpA + 16 * 64;
    const ushort* gmpA = gm + ((size_t)b * 1024 + q0 + l15) * 1024;
    const ushort* gmpB = gmpA + 16 * 1024;

    const short8 qa0 = *(const short8*)(QpA + g * 8);
    const short8 qa1 = *(const short8*)(QpA + 32 + g * 8);
    const short8 qb0 = *(const short8*)(QpB + g * 8);
    const short8 qb1 = *(const short8*)(QpB + 32 + g * 8);

    // staging: LDS row p holds K global row gk(p) (sigma perm), V row p (id).
    const int cb = (lane & 7) << 4;
    const int rA = wave * 8 + (lane >> 3);
    const int rB = rA + 32;
    const int gkA = (rA & 3) + 4 * ((rA >> 4) & 1) + 8 * ((rA >> 2) & 3) + 32 * (rA >> 5);
    const int gkB = (rB & 3) + 4 * ((rB >> 4) & 1) + 8 * ((rB >> 2) & 3) + 32 * (rB >> 5);
    const int okA = gkA * 128 + (cb ^ ((rA & 7) << 4));
    const int okB = gkB * 128 + (cb ^ ((rB & 7) << 4));
    const int ovA = rA * 2048 + (cb ^ ((rA & 7) << 4));
    const int ovB = rB * 2048 + (cb ^ ((rB & 7) << 4));

    const int sw = (l15 & 7) << 4;
    const int c0 = (g * 16) ^ sw;
    const int c1 = (64 + g * 16) ^ sw;

    f32x4 otA[4], otB[4];
    #pragma unroll
    for (int t = 0; t < 4; ++t) {
        otA[t] = (f32x4){0.f, 0.f, 0.f, 0.f};
        otB[t] = (f32x4){0.f, 0.f, 0.f, 0.f};
    }
    float lsA = 0.f, lsB = 0.f;
    f32x4 sEA[4], sEB[4], sOA[4], sOB[4];
    short8 gcA0, gcA1, gcB0, gcB1;

    // prologue: stage tiles 0,1 -> buf 0,1; gm(0) -> regs; QK(0) -> sE
    gl16(Kpb + okA, &kv[0][0][wave * 512]);
    gl16(Kpb + okB, &kv[0][0][(4 + wave) * 512]);
    gl16(Vpb + ovA, &kv[0][1][wave * 512]);
    gl16(Vpb + ovB, &kv[0][1][(4 + wave) * 512]);
    gl16(Kpb + 8192 + okA, &kv[1][0][wave * 512]);
    gl16(Kpb + 8192 + okB, &kv[1][0][(4 + wave) * 512]);
    gl16(Vpb + 128 + ovA, &kv[1][1][wave * 512]);
    gl16(Vpb + 128 + ovB, &kv[1][1][(4 + wave) * 512]);
    gcA0 = *(const short8*)(gmpA + g * 8);
    gcA1 = *(const short8*)(gmpA + 32 + g * 8);
    gcB0 = *(const short8*)(gmpB + g * 8);
    gcB1 = *(const short8*)(gmpB + 32 + g * 8);
    __syncthreads();
    QKX(0, sEA, sEB);

    TILEX(0,  0, 1, 2, sEA, sEB, sOA, sOB);
    TILEX(1,  1, 2, 0, sOA, sOB, sEA, sEB);
    TILEX(2,  2, 0, 1, sEA, sEB, sOA, sOB);
    TILEX(3,  0, 1, 2, sOA, sOB, sEA, sEB);
    TILEX(4,  1, 2, 0, sEA, sEB, sOA, sOB);
    TILEX(5,  2, 0, 1, sOA, sOB, sEA, sEB);
    TILEX(6,  0, 1, 2, sEA, sEB, sOA, sOB);
    TILEX(7,  1, 2, 0, sOA, sOB, sEA, sEB);
    TILEX(8,  2, 0, 1, sEA, sEB, sOA, sOB);
    TILEX(9,  0, 1, 2, sOA, sOB, sEA, sEB);
    TILEX(10, 1, 2, 0, sEA, sEB, sOA, sOB);
    TILEX(11, 2, 0, 1, sOA, sOB, sEA, sEB);
    TILEX(12, 0, 1, 2, sEA, sEB, sOA, sOB);
    TILEX(13, 1, 2, 0, sOA, sOB, sEA, sEB);
    TILEX(14, 2, 0, 1, sEA, sEB, sOA, sOB);
    TILEX(15, 0, 1, 2, sOA, sOB, sEA, sEB);

    lsA += __shfl_xor(lsA, 16, 64);
    lsA += __shfl_xor(lsA, 32, 64);
    lsB += __shfl_xor(lsB, 16, 64);
    lsB += __shfl_xor(lsB, 32, 64);
    const float invA = 1.0f / lsA;
    const float invB = 1.0f / lsB;

    ushort* xpA = xo + ((size_t)bh * 1024 + q0 + l15) * 64;
    ushort* xpB = xpA + 16 * 64;
    #pragma unroll
    for (int td = 0; td < 4; ++td) {
        uint2 oa, ob;
        oa.x = cvtpk(otA[td][0] * invA, otA[td][1] * invA);
        oa.y = cvtpk(otA[td][2] * invA, otA[td][3] * invA);
        ob.x = cvtpk(otB[td][0] * invB, otB[td][1] * invB);
        ob.y = cvtpk(otB[td][2] * invB, otB[td][3] * invB);
        *(uint2*)(xpA + td * 16 + g * 4) = oa;
        *(uint2*)(xpB + td * 16 + g * 4) = ob;
    }
}

// ---------------------------------------------------------------------------
extern "C" void kernel_launch(void* const* d_in, const int* in_sizes, int n_in,
                              void* d_out, int out_size, void* d_ws, size_t ws_size,
                              hipStream_t stream)
{
    const float* query = (const float*)d_in[0];
    const float* key   = (const float*)d_in[1];
    const float* value = (const float*)d_in[2];
    const float* gprob = (const float*)d_in[3];
    const float* Wq    = (const float*)d_in[4];
    const float* Wk    = (const float*)d_in[5];
    const float* Wv    = (const float*)d_in[6];
    const float* Wh    = (const float*)d_in[7];
    const float* bh    = (const float*)d_in[8];
    const int*   mask  = (const int*)d_in[9];
    float* out = (float*)d_out;

    ushort* ws = (ushort*)d_ws;
    const size_t HS = (size_t)64 * 65536;   // 4,194,304
    ushort* q_ws = ws;
    ushort* k_ws = ws + HS;
    ushort* vT   = ws + 2 * HS;
    ushort* gmb  = ws + 3 * HS;             // 2*HS elems
    ushort* qb   = ws + 5 * HS;
    ushort* kb   = ws + 6 * HS;
    ushort* vb   = ws + 7 * HS;
    ushort* wqb  = ws + 8 * HS;
    ushort* wkb  = wqb + 262144;
    ushort* wvb  = wkb + 262144;
    ushort* whb  = wvb + 262144;
    ushort* x_ws = qb;                      // alias: qb dead after gemm3

    prep<<<21504, 256, 0, stream>>>(query, key, value, Wq, Wk, Wv, Wh,
                                    mask, gprob, qb, kb, vb,
                                    wqb, wkb, wvb, whb, gmb);
    gemm3<<<dim3(64, 4, 3), 256, 0, stream>>>(qb, kb, vb, wqb, wkb, wvb,
                                              q_ws, k_ws, vT);
    attn<<<512, 256, 0, stream>>>(q_ws, k_ws, vT, gmb, x_ws);
    gemm_o<<<dim3(64, 4), 256, 0, stream>>>(x_ws, whb, bh, out);
}